// Round 14
// baseline (691.489 us; speedup 1.0000x reference)
//
#include <hip/hip_runtime.h>
#include <math.h>

#define D_    1024
#define ED_   2048
#define NST   32
#define KCONV 4
#define DTR_  64
#define L_    1024
#define NB_   4
#define NCH   8
#define CHUNK (L_ / NCH)
#define ZSPL  4
#define XPZ   16

typedef __bf16 bf16_8 __attribute__((ext_vector_type(8)));
typedef __bf16 bf16_4 __attribute__((ext_vector_type(4)));
typedef float  f32x4  __attribute__((ext_vector_type(4)));

__device__ __forceinline__ float softplus_f(float x) {
  return x > 20.f ? x : log1pf(expf(x));
}
__device__ __forceinline__ float silu_f(float x) {
  return x / (1.f + expf(-x));
}

// XCD-aware bijective remap (nwg % 8 == 0 for all our GEMM grids)
__device__ __forceinline__ int xcd_swz(int lin, int nwg) {
  const int q = nwg >> 3;
  return (lin & 7) * q + (lin >> 3);
}

// segmented fp32 -> bf16 (each count multiple of 8)
__global__ __launch_bounds__(256) void f2bf4_k(
    const float* __restrict__ i0, __bf16* __restrict__ o0, int n0,
    const float* __restrict__ i1, __bf16* __restrict__ o1, int n1,
    const float* __restrict__ i2, __bf16* __restrict__ o2, int n2,
    const float* __restrict__ i3, __bf16* __restrict__ o3, int n3)
{
  int gid = blockIdx.x * 256 + threadIdx.x;
  const int u0 = n0 >> 3, u1 = n1 >> 3, u2 = n2 >> 3, u3 = n3 >> 3;
  const float* in; __bf16* out;
  if (gid < u0) { in = i0; out = o0; }
  else if ((gid -= u0) < u1) { in = i1; out = o1; }
  else if ((gid -= u1) < u2) { in = i2; out = o2; }
  else if ((gid -= u2) < u3) { in = i3; out = o3; }
  else return;
  const int i = gid * 8;
  const float4 a = *reinterpret_cast<const float4*>(in + i);
  const float4 b = *reinterpret_cast<const float4*>(in + i + 4);
  bf16_8 v;
  v[0]=(__bf16)a.x; v[1]=(__bf16)a.y; v[2]=(__bf16)a.z; v[3]=(__bf16)a.w;
  v[4]=(__bf16)b.x; v[5]=(__bf16)b.y; v[6]=(__bf16)b.z; v[7]=(__bf16)b.w;
  *reinterpret_cast<bf16_8*>(out + i) = v;
}

// ---- MFMA bf16 GEMM (128x128, BK=64, XOR-swizzled LDS, XCD-swizzled grid) ----
// flags: 1=accumulate, 2=softplus, 4=bias, 8=write bf16 output (C cast to __bf16*)
__global__ __launch_bounds__(256) void gemm_mfma(
    const __bf16* __restrict__ A, int lda,
    const __bf16* __restrict__ W, int ldw,
    const float* __restrict__ bias, float* __restrict__ C, int ldc,
    int K, int flags)
{
  __shared__ __bf16 As[128 * 64];
  __shared__ __bf16 Ws[128 * 64];
  const int tid  = threadIdx.x;
  const int lane = tid & 63;
  const int w    = tid >> 6;
  const int wr   = w >> 1, wc = w & 1;
  const int nwg  = gridDim.x * gridDim.y;
  const int swz  = xcd_swz(blockIdx.y * gridDim.x + blockIdx.x, nwg);
  const int bx   = swz % gridDim.x, by = swz / gridDim.x;
  const int row0 = by * 128, col0 = bx * 128;

  f32x4 acc[4][4] = {};

  for (int k0 = 0; k0 < K; k0 += 64) {
    #pragma unroll
    for (int j = 0; j < 4; ++j) {
      const int inst = w * 4 + j;
      const int row  = inst * 8 + (lane >> 3);
      const int lu   = (lane & 7) ^ (row & 7);
      __builtin_amdgcn_global_load_lds(
          (const __attribute__((address_space(1))) void*)(A + (size_t)(row0 + row) * lda + k0 + lu * 8),
          (__attribute__((address_space(3))) void*)(&As[inst * 512]), 16, 0, 0);
      __builtin_amdgcn_global_load_lds(
          (const __attribute__((address_space(1))) void*)(W + (size_t)(col0 + row) * ldw + k0 + lu * 8),
          (__attribute__((address_space(3))) void*)(&Ws[inst * 512]), 16, 0, 0);
    }
    __syncthreads();
    const int r16 = lane & 15;
    const int uq  = lane >> 4;
    #pragma unroll
    for (int ks = 0; ks < 2; ++ks) {
      bf16_8 af[4], bfr[4];
      #pragma unroll
      for (int m = 0; m < 4; ++m) {
        const int row = wr * 64 + m * 16 + r16;
        const int pu  = (ks * 4 + uq) ^ (row & 7);
        af[m] = *reinterpret_cast<const bf16_8*>(&As[row * 64 + pu * 8]);
      }
      #pragma unroll
      for (int n = 0; n < 4; ++n) {
        const int row = wc * 64 + n * 16 + r16;
        const int pu  = (ks * 4 + uq) ^ (row & 7);
        bfr[n] = *reinterpret_cast<const bf16_8*>(&Ws[row * 64 + pu * 8]);
      }
      #pragma unroll
      for (int m = 0; m < 4; ++m)
        #pragma unroll
        for (int n = 0; n < 4; ++n)
          acc[m][n] = __builtin_amdgcn_mfma_f32_16x16x32_bf16(af[m], bfr[n], acc[m][n], 0, 0, 0);
    }
    __syncthreads();
  }

  const int crow = (lane >> 4) * 4;
  const int ccol = lane & 15;
  __bf16* Cb = reinterpret_cast<__bf16*>(C);
  #pragma unroll
  for (int m = 0; m < 4; ++m)
    #pragma unroll
    for (int n = 0; n < 4; ++n) {
      const int col = col0 + wc * 64 + n * 16 + ccol;
      const float bv = (flags & 4) ? bias[col] : 0.f;
      #pragma unroll
      for (int r = 0; r < 4; ++r) {
        const int row = row0 + wr * 64 + m * 16 + crow + r;
        float v = acc[m][n][r] + bv;
        if (flags & 2) v = softplus_f(v);
        if (flags & 8) {
          Cb[(size_t)row * ldc + col] = (__bf16)v;
        } else {
          float* cp = C + (size_t)row * ldc + col;
          if (flags & 1) v += *cp;
          *cp = v;
        }
      }
    }
}

// split-K MFMA GEMM (lda=ldw=K)
__global__ __launch_bounds__(256) void gemm_mfma_sk(
    const __bf16* __restrict__ A, const __bf16* __restrict__ W,
    float* __restrict__ partials, int M, int N, int K, int Kc)
{
  __shared__ __bf16 As[128 * 64];
  __shared__ __bf16 Ws[128 * 64];
  const int tid  = threadIdx.x;
  const int lane = tid & 63;
  const int w    = tid >> 6;
  const int wr   = w >> 1, wc = w & 1;
  const int nwg  = gridDim.x * gridDim.y * gridDim.z;
  const int lin  = (blockIdx.z * gridDim.y + blockIdx.y) * gridDim.x + blockIdx.x;
  const int swz  = xcd_swz(lin, nwg);
  const int bx   = swz % gridDim.x;
  const int tmp  = swz / gridDim.x;
  const int by   = tmp % gridDim.y, bz = tmp / gridDim.y;
  const int row0 = by * 128, col0 = bx * 128;
  const int kbase = bz * Kc;

  f32x4 acc[4][4] = {};

  for (int k0 = kbase; k0 < kbase + Kc; k0 += 64) {
    #pragma unroll
    for (int j = 0; j < 4; ++j) {
      const int inst = w * 4 + j;
      const int row  = inst * 8 + (lane >> 3);
      const int lu   = (lane & 7) ^ (row & 7);
      __builtin_amdgcn_global_load_lds(
          (const __attribute__((address_space(1))) void*)(A + (size_t)(row0 + row) * K + k0 + lu * 8),
          (__attribute__((address_space(3))) void*)(&As[inst * 512]), 16, 0, 0);
      __builtin_amdgcn_global_load_lds(
          (const __attribute__((address_space(1))) void*)(W + (size_t)(col0 + row) * K + k0 + lu * 8),
          (__attribute__((address_space(3))) void*)(&Ws[inst * 512]), 16, 0, 0);
    }
    __syncthreads();
    const int r16 = lane & 15;
    const int uq  = lane >> 4;
    #pragma unroll
    for (int ks = 0; ks < 2; ++ks) {
      bf16_8 af[4], bfr[4];
      #pragma unroll
      for (int m = 0; m < 4; ++m) {
        const int row = wr * 64 + m * 16 + r16;
        const int pu  = (ks * 4 + uq) ^ (row & 7);
        af[m] = *reinterpret_cast<const bf16_8*>(&As[row * 64 + pu * 8]);
      }
      #pragma unroll
      for (int n = 0; n < 4; ++n) {
        const int row = wc * 64 + n * 16 + r16;
        const int pu  = (ks * 4 + uq) ^ (row & 7);
        bfr[n] = *reinterpret_cast<const bf16_8*>(&Ws[row * 64 + pu * 8]);
      }
      #pragma unroll
      for (int m = 0; m < 4; ++m)
        #pragma unroll
        for (int n = 0; n < 4; ++n)
          acc[m][n] = __builtin_amdgcn_mfma_f32_16x16x32_bf16(af[m], bfr[n], acc[m][n], 0, 0, 0);
    }
    __syncthreads();
  }

  float* base = partials + (size_t)bz * M * N;
  const int crow = (lane >> 4) * 4;
  const int ccol = lane & 15;
  #pragma unroll
  for (int m = 0; m < 4; ++m)
    #pragma unroll
    for (int n = 0; n < 4; ++n) {
      const int col = col0 + wc * 64 + n * 16 + ccol;
      #pragma unroll
      for (int r = 0; r < 4; ++r) {
        const int row = row0 + wr * 64 + m * 16 + crow + r;
        base[(size_t)row * N + col] = acc[m][n][r];
      }
    }
}

// generic reduce (xproj + final out-reduce)
__global__ __launch_bounds__(256) void mfma_sk_reduce(
    const float* __restrict__ partials, const float* __restrict__ bias,
    float* __restrict__ C, __bf16* __restrict__ Cbf,
    int elems, int ncols, int nz, int flags)
{
  const int i = (blockIdx.x * 256 + threadIdx.x) * 4;
  if (i >= elems) return;
  float4 s = *reinterpret_cast<const float4*>(partials + i);
  for (int z = 1; z < nz; ++z) {
    const float4 p = *reinterpret_cast<const float4*>(partials + (size_t)z * elems + i);
    s.x += p.x; s.y += p.y; s.z += p.z; s.w += p.w;
  }
  if (flags & 4) {
    const float4 bv = *reinterpret_cast<const float4*>(bias + (i % ncols));
    s.x += bv.x; s.y += bv.y; s.z += bv.z; s.w += bv.w;
  }
  if (flags & 1) {
    const float4 ov = *reinterpret_cast<const float4*>(C + i);
    s.x += ov.x; s.y += ov.y; s.z += ov.z; s.w += ov.w;
  }
  *reinterpret_cast<float4*>(C + i) = s;
  if (flags & 8) {
    bf16_4 b;
    b[0]=(__bf16)s.x; b[1]=(__bf16)s.y; b[2]=(__bf16)s.z; b[3]=(__bf16)s.w;
    *reinterpret_cast<bf16_4*>(Cbf + i) = b;
  }
}

// fused: reduce 4 split-K partials (+bias or +acc) -> h_buf, then LayerNorm -> bf16
__global__ __launch_bounds__(256) void reduce_ln_k(
    const float* __restrict__ partials, const float* __restrict__ bias,
    float* __restrict__ hbuf, const float* __restrict__ g,
    const float* __restrict__ b, __bf16* __restrict__ outbf, int flags)
{
  __shared__ float red[8];
  const int row = blockIdx.x;
  const int tid = threadIdx.x;
  const int c = tid * 4;
  const size_t off = (size_t)row * D_ + c;
  float4 v = *reinterpret_cast<const float4*>(partials + off);
  #pragma unroll
  for (int z = 1; z < ZSPL; ++z) {
    const float4 p = *reinterpret_cast<const float4*>(partials + (size_t)z * (L_*D_) + off);
    v.x += p.x; v.y += p.y; v.z += p.z; v.w += p.w;
  }
  if (flags & 4) {
    const float4 bv = *reinterpret_cast<const float4*>(bias + c);
    v.x += bv.x; v.y += bv.y; v.z += bv.z; v.w += bv.w;
  }
  if (flags & 1) {
    const float4 ov = *reinterpret_cast<const float4*>(hbuf + off);
    v.x += ov.x; v.y += ov.y; v.z += ov.z; v.w += ov.w;
  }
  *reinterpret_cast<float4*>(hbuf + off) = v;

  float s = v.x + v.y + v.z + v.w;
  #pragma unroll
  for (int o = 32; o; o >>= 1) s += __shfl_down(s, o, 64);
  if ((tid & 63) == 0) red[tid >> 6] = s;
  __syncthreads();
  const float m = (red[0] + red[1] + red[2] + red[3]) * (1.f / D_);
  float dx0 = v.x - m, dx1 = v.y - m, dx2 = v.z - m, dx3 = v.w - m;
  float ss = dx0*dx0 + dx1*dx1 + dx2*dx2 + dx3*dx3;
  #pragma unroll
  for (int o = 32; o; o >>= 1) ss += __shfl_down(ss, o, 64);
  if ((tid & 63) == 0) red[4 + (tid >> 6)] = ss;
  __syncthreads();
  const float var = (red[4] + red[5] + red[6] + red[7]) * (1.f / D_);
  const float rs = rsqrtf(var + 1e-5f);
  const float4 gv = *reinterpret_cast<const float4*>(g + c);
  const float4 bv = *reinterpret_cast<const float4*>(b + c);
  bf16_4 o;
  o[0] = (__bf16)(dx0 * rs * gv.x + bv.x);
  o[1] = (__bf16)(dx1 * rs * gv.y + bv.y);
  o[2] = (__bf16)(dx2 * rs * gv.z + bv.z);
  o[3] = (__bf16)(dx3 * rs * gv.w + bv.w);
  *reinterpret_cast<bf16_4*>(outbf + off) = o;
}

// layernorm, fp32 out (final LN)
__global__ __launch_bounds__(256) void layernorm_k(
    const float* __restrict__ x, const float* __restrict__ g,
    const float* __restrict__ b, float* __restrict__ out)
{
  __shared__ float red[8];
  const int row = blockIdx.x;
  const int tid = threadIdx.x;
  const float* xr = x + (size_t)row * D_;
  float4 v = *reinterpret_cast<const float4*>(xr + tid * 4);
  float s = v.x + v.y + v.z + v.w;
  #pragma unroll
  for (int off = 32; off; off >>= 1) s += __shfl_down(s, off, 64);
  if ((tid & 63) == 0) red[tid >> 6] = s;
  __syncthreads();
  const float m = (red[0] + red[1] + red[2] + red[3]) * (1.f / D_);
  float dx0 = v.x - m, dx1 = v.y - m, dx2 = v.z - m, dx3 = v.w - m;
  float ss = dx0*dx0 + dx1*dx1 + dx2*dx2 + dx3*dx3;
  #pragma unroll
  for (int off = 32; off; off >>= 1) ss += __shfl_down(ss, off, 64);
  if ((tid & 63) == 0) red[4 + (tid >> 6)] = ss;
  __syncthreads();
  const float var = (red[4] + red[5] + red[6] + red[7]) * (1.f / D_);
  const float rs = rsqrtf(var + 1e-5f);
  const int c = tid * 4;
  const float4 gv = *reinterpret_cast<const float4*>(g + c);
  const float4 bv = *reinterpret_cast<const float4*>(b + c);
  float4 o;
  o.x = dx0 * rs * gv.x + bv.x;
  o.y = dx1 * rs * gv.y + bv.y;
  o.z = dx2 * rs * gv.z + bv.z;
  o.w = dx3 * rs * gv.w + bv.w;
  *reinterpret_cast<float4*>(out + (size_t)row * D_ + c) = o;
}

// depthwise causal conv K=4 + bias + silu; 8 timesteps/thread; bf16 in, bf16 out
__global__ __launch_bounds__(256) void conv_silu_k(
    const __bf16* __restrict__ xzb, const float* __restrict__ cw,
    const float* __restrict__ cb, __bf16* __restrict__ ub)
{
  const int e = blockIdx.x * 256 + threadIdx.x;
  const int t0 = blockIdx.y * 8;
  const float w0 = cw[e*4+0], w1 = cw[e*4+1], w2 = cw[e*4+2], w3 = cw[e*4+3];
  const float b = cb[e];
  float x0 = (t0 >= 3) ? (float)xzb[(size_t)(t0-3)*(2*ED_)+e] : 0.f;
  float x1 = (t0 >= 2) ? (float)xzb[(size_t)(t0-2)*(2*ED_)+e] : 0.f;
  float x2 = (t0 >= 1) ? (float)xzb[(size_t)(t0-1)*(2*ED_)+e] : 0.f;
  #pragma unroll
  for (int j = 0; j < 8; ++j) {
    const float x3 = (float)xzb[(size_t)(t0+j)*(2*ED_)+e];
    const float uv = silu_f(b + w0*x0 + w1*x1 + w2*x2 + w3*x3);
    ub[(size_t)(t0+j)*ED_+e] = (__bf16)uv;
    x0 = x1; x1 = x2; x2 = x3;
  }
}

// ---- chunked selective scan (512-thread / 16-channel blocks) ----
// phase 1: local scan -> hend, Pend. 32-step tiles, chain unrolled x2. u from bf16.
__global__ __launch_bounds__(512) void scan_phase1(
    const float* __restrict__ delta, const __bf16* __restrict__ ub,
    const float* __restrict__ xdbl, const float* __restrict__ A_log,
    float* __restrict__ hend, float* __restrict__ Pend)
{
  __shared__ float dl[32][16], ul[32][16];
  __shared__ float bl[32][36];
  const int tid = threadIdx.x;
  const int n = tid & 31;
  const int c = tid >> 5;
  const int e0 = blockIdx.x * 16;
  const int e = e0 + c;
  const int ch = blockIdx.y;
  const float a = -expf(A_log[e * NST + n]);
  float h = 0.f, S = 0.f;
  const int t0 = ch * CHUNK;
  const int s_t = tid >> 4, s_e = tid & 15;
  const int b_t = tid >> 3, b_c = (tid & 7) * 4;

  float rg_d, rg_u;
  float4 rg_b;
  rg_d = delta[(size_t)(t0 + s_t) * ED_ + e0 + s_e];
  rg_u = (float)ub[(size_t)(t0 + s_t) * ED_ + e0 + s_e];
  if (tid < 256)
    rg_b = *reinterpret_cast<const float4*>(&xdbl[(size_t)(t0 + b_t) * 128 + 64 + b_c]);

  for (int tb = 0; tb < CHUNK; tb += 32) {
    dl[s_t][s_e] = rg_d;
    ul[s_t][s_e] = rg_u;
    if (tid < 256) *reinterpret_cast<float4*>(&bl[b_t][b_c]) = rg_b;
    __syncthreads();
    if (tb + 32 < CHUNK) {
      const int t = t0 + tb + 32 + s_t;
      rg_d = delta[(size_t)t * ED_ + e0 + s_e];
      rg_u = (float)ub[(size_t)t * ED_ + e0 + s_e];
      if (tid < 256)
        rg_b = *reinterpret_cast<const float4*>(&xdbl[(size_t)(t0 + tb + 32 + b_t) * 128 + 64 + b_c]);
    }
    #pragma unroll
    for (int jp = 0; jp < 16; ++jp) {
      const float sd1 = dl[2*jp][c],   uv1 = ul[2*jp][c],   B1 = bl[2*jp][n];
      const float sd2 = dl[2*jp+1][c], uv2 = ul[2*jp+1][c], B2 = bl[2*jp+1][n];
      const float dA1 = __expf(sd1 * a);
      const float dA2 = __expf(sd2 * a);
      const float b1 = sd1 * uv1 * B1;
      const float b2 = sd2 * uv2 * B2;
      h = fmaf(dA1 * dA2, h, fmaf(dA2, b1, b2));
      S += sd1 + sd2;
    }
    __syncthreads();
  }
  const int idx = ch * (ED_ * NST) + blockIdx.x * 512 + tid;
  hend[idx] = h;
  Pend[idx] = __expf(a * S);
}

// phase 3: inline combine + pipelined tiles + f32 p_lds + 2 barriers/tile
__global__ __launch_bounds__(512) void scan_phase3(
    const float* __restrict__ delta, const __bf16* __restrict__ ub,
    const float* __restrict__ xdbl, const float* __restrict__ A_log,
    const float* __restrict__ hend, const float* __restrict__ Pend,
    const float* __restrict__ Dp,
    const __bf16* __restrict__ xzb, __bf16* __restrict__ y)
{
  __shared__ float p_lds[16][16][33];            // 33792 B
  __shared__ float dl[16][16], ul[16][16], zl[16][16];  // 3072 B
  __shared__ float bc[16][68];                   // 4352 B
  const int tid = threadIdx.x;
  const int n = tid & 31;
  const int c = tid >> 5;
  const int e0 = blockIdx.x * 16;
  const int e = e0 + c;
  const int ch = blockIdx.y;
  const float a = -expf(A_log[e * NST + n]);
  const float dp = Dp[e];

  float h = 0.f;
  {
    const int sidx = blockIdx.x * 512 + tid;
    for (int cc = 0; cc < ch; ++cc) {
      const int off = cc * (ED_ * NST) + sidx;
      h = fmaf(Pend[off], h, hend[off]);
    }
  }

  const int t0 = ch * CHUNK;
  const int r = n & 15, half = n >> 4;
  const int s_t  = (tid & 255) >> 4;
  const int s_e  = tid & 15;
  const int bidx = tid - 256;
  const int b_t  = (bidx & 255) >> 4;
  const int b_c  = (bidx & 15) * 4;

  float rg_a = 0.f, rg_z = 0.f;
  float4 rg_bc;
  {
    const int t = t0 + s_t;
    if (tid < 256) {
      rg_a = delta[(size_t)t * ED_ + e0 + s_e];
      rg_z = (float)xzb[(size_t)t * (2*ED_) + ED_ + e0 + s_e];
    } else {
      rg_a = (float)ub[(size_t)t * ED_ + e0 + s_e];
      rg_bc = *reinterpret_cast<const float4*>(&xdbl[(size_t)(t0 + b_t) * 128 + 64 + b_c]);
    }
  }

  for (int tb = 0; tb < CHUNK; tb += 16) {
    if (tid < 256) {
      dl[s_t][s_e] = rg_a; zl[s_t][s_e] = rg_z;
    } else {
      ul[s_t][s_e] = rg_a;
      *reinterpret_cast<float4*>(&bc[b_t][b_c]) = rg_bc;
    }
    __syncthreads();                       // B1: stage visible
    if (tb + 16 < CHUNK) {
      const int t = t0 + tb + 16 + s_t;
      if (tid < 256) {
        rg_a = delta[(size_t)t * ED_ + e0 + s_e];
        rg_z = (float)xzb[(size_t)t * (2*ED_) + ED_ + e0 + s_e];
      } else {
        rg_a = (float)ub[(size_t)t * ED_ + e0 + s_e];
        rg_bc = *reinterpret_cast<const float4*>(&xdbl[(size_t)(t0 + tb + 16 + b_t) * 128 + 64 + b_c]);
      }
    }
    #pragma unroll
    for (int jp = 0; jp < 8; ++jp) {
      const float sd1 = dl[2*jp][c],   uv1 = ul[2*jp][c];
      const float sd2 = dl[2*jp+1][c], uv2 = ul[2*jp+1][c];
      const float B1 = bc[2*jp][n],   C1 = bc[2*jp][32 + n];
      const float B2 = bc[2*jp+1][n], C2 = bc[2*jp+1][32 + n];
      const float dA1 = __expf(sd1 * a);
      const float dA2 = __expf(sd2 * a);
      const float b1 = sd1 * uv1 * B1;
      const float b2 = sd2 * uv2 * B2;
      const float h1 = fmaf(dA1, h, b1);
      p_lds[c][2*jp][n] = h1 * C1;
      h = fmaf(dA1 * dA2, h, fmaf(dA2, b1, b2));
      p_lds[c][2*jp+1][n] = h * C2;
    }
    // hoist epilogue operands BEFORE p_lds barrier so no trailing barrier needed
    const float uvt = ul[r][c];
    const float zv  = zl[r][c];
    __syncthreads();                       // B2: p_lds visible
    float s = 0.f;
    #pragma unroll
    for (int k = 0; k < 16; ++k) s += p_lds[c][r][half * 16 + k];
    s += __shfl_xor(s, 16, 64);
    if (half == 0) {
      y[(size_t)(t0 + tb + r) * ED_ + e] = (__bf16)((s + uvt * dp) * silu_f(zv));
    }
    // no B3: next iteration's stage writes touch only dl/ul/zl/bc; reduce reads
    // only p_lds, whose next writes occur after B1 (which all threads must pass).
  }
}

// column-mean partials (coalesced)
__global__ __launch_bounds__(256) void colmean_part_k(
    const float* __restrict__ hf, float* __restrict__ part)
{
  const int d = blockIdx.x * 256 + threadIdx.x;
  const int tc = blockIdx.y;
  float s = 0.f;
  #pragma unroll 8
  for (int j = 0; j < 32; ++j) s += hf[(size_t)(tc * 32 + j) * D_ + d];
  part[tc * D_ + d] = s;
}

// fused finalize + state projection
__global__ __launch_bounds__(256) void state_fused_k(
    const float* __restrict__ part, const float* __restrict__ spw,
    const float* __restrict__ spb, float* __restrict__ out)
{
  __shared__ float red[4];
  const int nidx = blockIdx.x;
  const int tid = threadIdx.x;
  float s = 0.f;
  for (int d = tid; d < D_; d += 256) {
    float cm = 0.f;
    #pragma unroll
    for (int c = 0; c < 32; ++c) cm += part[c * D_ + d];
    s += cm * (1.f / L_) * spw[(size_t)nidx * D_ + d];
  }
  #pragma unroll
  for (int off = 32; off; off >>= 1) s += __shfl_down(s, off, 64);
  if ((tid & 63) == 0) red[tid >> 6] = s;
  __syncthreads();
  if (tid == 0) out[nidx] = red[0] + red[1] + red[2] + red[3] + spb[nidx];
}

extern "C" void kernel_launch(void* const* d_in, const int* in_sizes, int n_in,
                              void* d_out, int out_size, void* d_ws, size_t ws_size,
                              hipStream_t stream) {
  const float* x        = (const float*)d_in[0];
  const float* Wi       = (const float*)d_in[1];
  const float* bi       = (const float*)d_in[2];
  const float* ln_g     = (const float*)d_in[3];
  const float* ln_b     = (const float*)d_in[4];
  const float* in_w     = (const float*)d_in[5];
  const float* conv_w   = (const float*)d_in[6];
  const float* conv_b   = (const float*)d_in[7];
  const float* xproj_w  = (const float*)d_in[8];
  const float* dtproj_w = (const float*)d_in[9];
  const float* dtproj_b = (const float*)d_in[10];
  const float* A_log    = (const float*)d_in[11];
  const float* Dp       = (const float*)d_in[12];
  const float* out_w    = (const float*)d_in[13];
  const float* fn_g     = (const float*)d_in[14];
  const float* fn_b     = (const float*)d_in[15];
  const float* sp_w     = (const float*)d_in[16];
  const float* sp_b     = (const float*)d_in[17];
  float* out  = (float*)d_out;
  float* ws_f = (float*)d_ws;

  float* h_buf  = ws_f;                // 1048576
  float* xz     = ws_f + 1048576;      // 4194304 (bf16 xz uses first half)
  float* u_buf  = ws_f + 5242880;      // 2097152 (fp32 u now dead; skmf overlay)
  float* xdbl   = ws_f + 7340032;      // 131072
  float* delta  = ws_f + 7471104;      // 2097152 (also xproj partials)
  float* hend   = ws_f + 9568256;      // 524288
  float* pend   = ws_f + 10092544;     // 524288
  __bf16* nbf   = (__bf16*)(ws_f + 10617856);  // 1M bf16
  __bf16* ybf   = (__bf16*)(ws_f + 11142144);  // 2M bf16
  __bf16* wbf   = (__bf16*)(ws_f + 12190720);  // 8M bf16 (in_w)
  __bf16* xdblbf= (__bf16*)(ws_f + 16385024);  // 128K bf16
  __bf16* dtwbf = (__bf16*)(ws_f + 16450560);  // 128K bf16
  __bf16* ubf   = (__bf16*)(ws_f + 16516096);  // 2M bf16
  __bf16* xpbf  = (__bf16*)(ws_f + 17564672);  // 256K bf16
  __bf16* owbf  = (__bf16*)(ws_f + 17695744);  // 2M bf16 (out_w)
  __bf16* xzb   = (__bf16*)xz;         // 4M bf16 (overlay xz slot)
  float* skmf   = u_buf;               // MFMA split-K partials overlay (Wi/out)
  float* skxp   = delta;               // xproj split-K partials overlay
  float* cmpart = hend;                // colmean partials overlay

  const dim3 blk(256);
  const dim3 blk512(512);

  // prologue: convert x + Wi; Wi GEMM split-K=4; fused reduce + LN(block 0)
  f2bf4_k<<<1024, blk, 0, stream>>>(x, nbf, L_*D_, Wi, wbf, D_*D_,
                                    x, nbf, 0, x, nbf, 0);
  gemm_mfma_sk<<<dim3(D_/128, L_/128, ZSPL), blk, 0, stream>>>(
      nbf, wbf, skmf, L_, D_, D_, D_/ZSPL);
  reduce_ln_k<<<L_, blk, 0, stream>>>(
      skmf, bi, h_buf, ln_g, ln_b, nbf, 4);

  for (int i = 0; i < NB_; ++i) {
    f2bf4_k<<<3264, blk, 0, stream>>>(
        in_w    + (size_t)i*2*ED_*D_, wbf,   2*ED_*D_,
        xproj_w + (size_t)i*128*ED_,  xpbf,  128*ED_,
        dtproj_w+ (size_t)i*ED_*DTR_, dtwbf, ED_*DTR_,
        out_w   + (size_t)i*D_*ED_,   owbf,  D_*ED_);
    // xz = normed @ in_w^T  (bf16 output)
    gemm_mfma<<<dim3(2*ED_/128, L_/128), blk, 0, stream>>>(
        nbf, D_, wbf, D_, nullptr, (float*)xzb, 2*ED_, D_, 8);
    conv_silu_k<<<dim3(ED_/256, L_/8), blk, 0, stream>>>(
        xzb, conv_w + (size_t)i*ED_*KCONV, conv_b + (size_t)i*ED_, ubf);
    // x_dbl = u @ xproj^T  (bf16 MFMA split-K=16)
    gemm_mfma_sk<<<dim3(1, L_/128, XPZ), blk, 0, stream>>>(
        ubf, xpbf, skxp, L_, 128, ED_, ED_/XPZ);
    mfma_sk_reduce<<<dim3(L_*128/4/256), blk, 0, stream>>>(
        skxp, nullptr, xdbl, xdblbf, L_*128, 128, XPZ, 8);
    // delta = softplus(dt @ dtproj^T + b)
    gemm_mfma<<<dim3(ED_/128, L_/128), blk, 0, stream>>>(
        xdblbf, 128, dtwbf, DTR_, dtproj_b + (size_t)i*ED_, delta, ED_, DTR_, 2 | 4);
    // chunked scan
    scan_phase1<<<dim3(ED_/16, NCH), blk512, 0, stream>>>(
        delta, ubf, xdbl, A_log + (size_t)i*ED_*NST, hend, pend);
    scan_phase3<<<dim3(ED_/16, NCH), blk512, 0, stream>>>(
        delta, ubf, xdbl, A_log + (size_t)i*ED_*NST, hend, pend,
        Dp + (size_t)i*ED_, xzb, ybf);
    // h += y @ out_w^T (split-K=4); fused reduce (+acc) + next LN
    gemm_mfma_sk<<<dim3(D_/128, L_/128, ZSPL), blk, 0, stream>>>(
        ybf, owbf, skmf, L_, D_, ED_, ED_/ZSPL);
    if (i < NB_ - 1) {
      reduce_ln_k<<<L_, blk, 0, stream>>>(
          skmf, nullptr, h_buf, ln_g + (i+1)*D_, ln_b + (i+1)*D_, nbf, 1);
    } else {
      mfma_sk_reduce<<<dim3(L_*D_/4/256), blk, 0, stream>>>(
          skmf, nullptr, h_buf, nullptr, L_*D_, D_, ZSPL, 1);
    }
  }

  layernorm_k<<<L_, blk, 0, stream>>>(h_buf, fn_g, fn_b, out);
  colmean_part_k<<<dim3(D_/256, 32), blk, 0, stream>>>(out, cmpart);
  state_fused_k<<<NST, blk, 0, stream>>>(cmpart, sp_w, sp_b, out + (size_t)L_*D_);
}

// Round 15
// 673.418 us; speedup vs baseline: 1.0268x; 1.0268x over previous
//
#include <hip/hip_runtime.h>
#include <math.h>

#define D_    1024
#define ED_   2048
#define NST   32
#define KCONV 4
#define DTR_  64
#define L_    1024
#define NB_   4
#define NCH   8
#define CHUNK (L_ / NCH)
#define ZSPL  4
#define XPZ   16

typedef __bf16 bf16_8 __attribute__((ext_vector_type(8)));
typedef __bf16 bf16_4 __attribute__((ext_vector_type(4)));
typedef float  f32x4  __attribute__((ext_vector_type(4)));

__device__ __forceinline__ float softplus_f(float x) {
  return x > 20.f ? x : log1pf(expf(x));
}
__device__ __forceinline__ float silu_f(float x) {
  return x / (1.f + expf(-x));
}

// XCD-aware bijective remap (nwg % 8 == 0 for all our GEMM grids)
__device__ __forceinline__ int xcd_swz(int lin, int nwg) {
  const int q = nwg >> 3;
  return (lin & 7) * q + (lin >> 3);
}

// segmented fp32 -> bf16 (each count multiple of 8)
__global__ __launch_bounds__(256) void f2bf4_k(
    const float* __restrict__ i0, __bf16* __restrict__ o0, int n0,
    const float* __restrict__ i1, __bf16* __restrict__ o1, int n1,
    const float* __restrict__ i2, __bf16* __restrict__ o2, int n2,
    const float* __restrict__ i3, __bf16* __restrict__ o3, int n3)
{
  int gid = blockIdx.x * 256 + threadIdx.x;
  const int u0 = n0 >> 3, u1 = n1 >> 3, u2 = n2 >> 3, u3 = n3 >> 3;
  const float* in; __bf16* out;
  if (gid < u0) { in = i0; out = o0; }
  else if ((gid -= u0) < u1) { in = i1; out = o1; }
  else if ((gid -= u1) < u2) { in = i2; out = o2; }
  else if ((gid -= u2) < u3) { in = i3; out = o3; }
  else return;
  const int i = gid * 8;
  const float4 a = *reinterpret_cast<const float4*>(in + i);
  const float4 b = *reinterpret_cast<const float4*>(in + i + 4);
  bf16_8 v;
  v[0]=(__bf16)a.x; v[1]=(__bf16)a.y; v[2]=(__bf16)a.z; v[3]=(__bf16)a.w;
  v[4]=(__bf16)b.x; v[5]=(__bf16)b.y; v[6]=(__bf16)b.z; v[7]=(__bf16)b.w;
  *reinterpret_cast<bf16_8*>(out + i) = v;
}

// ---- MFMA bf16 GEMM (128x128, BK=64, XOR-swizzled LDS, XCD-swizzled grid) ----
// flags: 1=accumulate, 2=softplus, 4=bias
__global__ __launch_bounds__(256) void gemm_mfma(
    const __bf16* __restrict__ A, int lda,
    const __bf16* __restrict__ W, int ldw,
    const float* __restrict__ bias, float* __restrict__ C, int ldc,
    int K, int flags)
{
  __shared__ __bf16 As[128 * 64];
  __shared__ __bf16 Ws[128 * 64];
  const int tid  = threadIdx.x;
  const int lane = tid & 63;
  const int w    = tid >> 6;
  const int wr   = w >> 1, wc = w & 1;
  const int nwg  = gridDim.x * gridDim.y;
  const int swz  = xcd_swz(blockIdx.y * gridDim.x + blockIdx.x, nwg);
  const int bx   = swz % gridDim.x, by = swz / gridDim.x;
  const int row0 = by * 128, col0 = bx * 128;

  f32x4 acc[4][4] = {};

  for (int k0 = 0; k0 < K; k0 += 64) {
    #pragma unroll
    for (int j = 0; j < 4; ++j) {
      const int inst = w * 4 + j;
      const int row  = inst * 8 + (lane >> 3);
      const int lu   = (lane & 7) ^ (row & 7);
      __builtin_amdgcn_global_load_lds(
          (const __attribute__((address_space(1))) void*)(A + (size_t)(row0 + row) * lda + k0 + lu * 8),
          (__attribute__((address_space(3))) void*)(&As[inst * 512]), 16, 0, 0);
      __builtin_amdgcn_global_load_lds(
          (const __attribute__((address_space(1))) void*)(W + (size_t)(col0 + row) * ldw + k0 + lu * 8),
          (__attribute__((address_space(3))) void*)(&Ws[inst * 512]), 16, 0, 0);
    }
    __syncthreads();
    const int r16 = lane & 15;
    const int uq  = lane >> 4;
    #pragma unroll
    for (int ks = 0; ks < 2; ++ks) {
      bf16_8 af[4], bfr[4];
      #pragma unroll
      for (int m = 0; m < 4; ++m) {
        const int row = wr * 64 + m * 16 + r16;
        const int pu  = (ks * 4 + uq) ^ (row & 7);
        af[m] = *reinterpret_cast<const bf16_8*>(&As[row * 64 + pu * 8]);
      }
      #pragma unroll
      for (int n = 0; n < 4; ++n) {
        const int row = wc * 64 + n * 16 + r16;
        const int pu  = (ks * 4 + uq) ^ (row & 7);
        bfr[n] = *reinterpret_cast<const bf16_8*>(&Ws[row * 64 + pu * 8]);
      }
      #pragma unroll
      for (int m = 0; m < 4; ++m)
        #pragma unroll
        for (int n = 0; n < 4; ++n)
          acc[m][n] = __builtin_amdgcn_mfma_f32_16x16x32_bf16(af[m], bfr[n], acc[m][n], 0, 0, 0);
    }
    __syncthreads();
  }

  const int crow = (lane >> 4) * 4;
  const int ccol = lane & 15;
  #pragma unroll
  for (int m = 0; m < 4; ++m)
    #pragma unroll
    for (int n = 0; n < 4; ++n) {
      const int col = col0 + wc * 64 + n * 16 + ccol;
      const float bv = (flags & 4) ? bias[col] : 0.f;
      #pragma unroll
      for (int r = 0; r < 4; ++r) {
        const int row = row0 + wr * 64 + m * 16 + crow + r;
        float* cp = C + (size_t)row * ldc + col;
        float v = acc[m][n][r] + bv;
        if (flags & 2) v = softplus_f(v);
        if (flags & 1) v += *cp;
        *cp = v;
      }
    }
}

// split-K MFMA GEMM (lda=ldw=K)
__global__ __launch_bounds__(256) void gemm_mfma_sk(
    const __bf16* __restrict__ A, const __bf16* __restrict__ W,
    float* __restrict__ partials, int M, int N, int K, int Kc)
{
  __shared__ __bf16 As[128 * 64];
  __shared__ __bf16 Ws[128 * 64];
  const int tid  = threadIdx.x;
  const int lane = tid & 63;
  const int w    = tid >> 6;
  const int wr   = w >> 1, wc = w & 1;
  const int nwg  = gridDim.x * gridDim.y * gridDim.z;
  const int lin  = (blockIdx.z * gridDim.y + blockIdx.y) * gridDim.x + blockIdx.x;
  const int swz  = xcd_swz(lin, nwg);
  const int bx   = swz % gridDim.x;
  const int tmp  = swz / gridDim.x;
  const int by   = tmp % gridDim.y, bz = tmp / gridDim.y;
  const int row0 = by * 128, col0 = bx * 128;
  const int kbase = bz * Kc;

  f32x4 acc[4][4] = {};

  for (int k0 = kbase; k0 < kbase + Kc; k0 += 64) {
    #pragma unroll
    for (int j = 0; j < 4; ++j) {
      const int inst = w * 4 + j;
      const int row  = inst * 8 + (lane >> 3);
      const int lu   = (lane & 7) ^ (row & 7);
      __builtin_amdgcn_global_load_lds(
          (const __attribute__((address_space(1))) void*)(A + (size_t)(row0 + row) * K + k0 + lu * 8),
          (__attribute__((address_space(3))) void*)(&As[inst * 512]), 16, 0, 0);
      __builtin_amdgcn_global_load_lds(
          (const __attribute__((address_space(1))) void*)(W + (size_t)(col0 + row) * K + k0 + lu * 8),
          (__attribute__((address_space(3))) void*)(&Ws[inst * 512]), 16, 0, 0);
    }
    __syncthreads();
    const int r16 = lane & 15;
    const int uq  = lane >> 4;
    #pragma unroll
    for (int ks = 0; ks < 2; ++ks) {
      bf16_8 af[4], bfr[4];
      #pragma unroll
      for (int m = 0; m < 4; ++m) {
        const int row = wr * 64 + m * 16 + r16;
        const int pu  = (ks * 4 + uq) ^ (row & 7);
        af[m] = *reinterpret_cast<const bf16_8*>(&As[row * 64 + pu * 8]);
      }
      #pragma unroll
      for (int n = 0; n < 4; ++n) {
        const int row = wc * 64 + n * 16 + r16;
        const int pu  = (ks * 4 + uq) ^ (row & 7);
        bfr[n] = *reinterpret_cast<const bf16_8*>(&Ws[row * 64 + pu * 8]);
      }
      #pragma unroll
      for (int m = 0; m < 4; ++m)
        #pragma unroll
        for (int n = 0; n < 4; ++n)
          acc[m][n] = __builtin_amdgcn_mfma_f32_16x16x32_bf16(af[m], bfr[n], acc[m][n], 0, 0, 0);
    }
    __syncthreads();
  }

  float* base = partials + (size_t)bz * M * N;
  const int crow = (lane >> 4) * 4;
  const int ccol = lane & 15;
  #pragma unroll
  for (int m = 0; m < 4; ++m)
    #pragma unroll
    for (int n = 0; n < 4; ++n) {
      const int col = col0 + wc * 64 + n * 16 + ccol;
      #pragma unroll
      for (int r = 0; r < 4; ++r) {
        const int row = row0 + wr * 64 + m * 16 + crow + r;
        base[(size_t)row * N + col] = acc[m][n][r];
      }
    }
}

// reduce nz partials -> C; flags: 1=acc into C, 4=bias(per col), 8=emit bf16 copy
__global__ __launch_bounds__(256) void mfma_sk_reduce(
    const float* __restrict__ partials, const float* __restrict__ bias,
    float* __restrict__ C, __bf16* __restrict__ Cbf,
    int elems, int ncols, int nz, int flags)
{
  const int i = (blockIdx.x * 256 + threadIdx.x) * 4;
  if (i >= elems) return;
  float4 s = *reinterpret_cast<const float4*>(partials + i);
  for (int z = 1; z < nz; ++z) {
    const float4 p = *reinterpret_cast<const float4*>(partials + (size_t)z * elems + i);
    s.x += p.x; s.y += p.y; s.z += p.z; s.w += p.w;
  }
  if (flags & 4) {
    const float4 bv = *reinterpret_cast<const float4*>(bias + (i % ncols));
    s.x += bv.x; s.y += bv.y; s.z += bv.z; s.w += bv.w;
  }
  if (flags & 1) {
    const float4 ov = *reinterpret_cast<const float4*>(C + i);
    s.x += ov.x; s.y += ov.y; s.z += ov.z; s.w += ov.w;
  }
  *reinterpret_cast<float4*>(C + i) = s;
  if (flags & 8) {
    bf16_4 b;
    b[0]=(__bf16)s.x; b[1]=(__bf16)s.y; b[2]=(__bf16)s.z; b[3]=(__bf16)s.w;
    *reinterpret_cast<bf16_4*>(Cbf + i) = b;
  }
}

// layernorm, fp32 out (final LN)
__global__ __launch_bounds__(256) void layernorm_k(
    const float* __restrict__ x, const float* __restrict__ g,
    const float* __restrict__ b, float* __restrict__ out)
{
  __shared__ float red[8];
  const int row = blockIdx.x;
  const int tid = threadIdx.x;
  const float* xr = x + (size_t)row * D_;
  float4 v = *reinterpret_cast<const float4*>(xr + tid * 4);
  float s = v.x + v.y + v.z + v.w;
  #pragma unroll
  for (int off = 32; off; off >>= 1) s += __shfl_down(s, off, 64);
  if ((tid & 63) == 0) red[tid >> 6] = s;
  __syncthreads();
  const float m = (red[0] + red[1] + red[2] + red[3]) * (1.f / D_);
  float dx0 = v.x - m, dx1 = v.y - m, dx2 = v.z - m, dx3 = v.w - m;
  float ss = dx0*dx0 + dx1*dx1 + dx2*dx2 + dx3*dx3;
  #pragma unroll
  for (int off = 32; off; off >>= 1) ss += __shfl_down(ss, off, 64);
  if ((tid & 63) == 0) red[4 + (tid >> 6)] = ss;
  __syncthreads();
  const float var = (red[4] + red[5] + red[6] + red[7]) * (1.f / D_);
  const float rs = rsqrtf(var + 1e-5f);
  const int c = tid * 4;
  const float4 gv = *reinterpret_cast<const float4*>(g + c);
  const float4 bv = *reinterpret_cast<const float4*>(b + c);
  float4 o;
  o.x = dx0 * rs * gv.x + bv.x;
  o.y = dx1 * rs * gv.y + bv.y;
  o.z = dx2 * rs * gv.z + bv.z;
  o.w = dx3 * rs * gv.w + bv.w;
  *reinterpret_cast<float4*>(out + (size_t)row * D_ + c) = o;
}

// layernorm with bf16 out
__global__ __launch_bounds__(256) void layernorm_bf_k(
    const float* __restrict__ x, const float* __restrict__ g,
    const float* __restrict__ b, __bf16* __restrict__ out)
{
  __shared__ float red[8];
  const int row = blockIdx.x;
  const int tid = threadIdx.x;
  const float* xr = x + (size_t)row * D_;
  float4 v = *reinterpret_cast<const float4*>(xr + tid * 4);
  float s = v.x + v.y + v.z + v.w;
  #pragma unroll
  for (int off = 32; off; off >>= 1) s += __shfl_down(s, off, 64);
  if ((tid & 63) == 0) red[tid >> 6] = s;
  __syncthreads();
  const float m = (red[0] + red[1] + red[2] + red[3]) * (1.f / D_);
  float dx0 = v.x - m, dx1 = v.y - m, dx2 = v.z - m, dx3 = v.w - m;
  float ss = dx0*dx0 + dx1*dx1 + dx2*dx2 + dx3*dx3;
  #pragma unroll
  for (int off = 32; off; off >>= 1) ss += __shfl_down(ss, off, 64);
  if ((tid & 63) == 0) red[4 + (tid >> 6)] = ss;
  __syncthreads();
  const float var = (red[4] + red[5] + red[6] + red[7]) * (1.f / D_);
  const float rs = rsqrtf(var + 1e-5f);
  const int c = tid * 4;
  const float4 gv = *reinterpret_cast<const float4*>(g + c);
  const float4 bv = *reinterpret_cast<const float4*>(b + c);
  bf16_4 o;
  o[0] = (__bf16)(dx0 * rs * gv.x + bv.x);
  o[1] = (__bf16)(dx1 * rs * gv.y + bv.y);
  o[2] = (__bf16)(dx2 * rs * gv.z + bv.z);
  o[3] = (__bf16)(dx3 * rs * gv.w + bv.w);
  *reinterpret_cast<bf16_4*>(out + (size_t)row * D_ + c) = o;
}

// depthwise causal conv K=4 + bias + silu; 8 timesteps/thread; fp32 + bf16 out
__global__ __launch_bounds__(256) void conv_silu_k(
    const float* __restrict__ xz, const float* __restrict__ cw,
    const float* __restrict__ cb, float* __restrict__ u, __bf16* __restrict__ ub)
{
  const int e = blockIdx.x * 256 + threadIdx.x;
  const int t0 = blockIdx.y * 8;
  const float w0 = cw[e*4+0], w1 = cw[e*4+1], w2 = cw[e*4+2], w3 = cw[e*4+3];
  const float b = cb[e];
  float x0 = (t0 >= 3) ? xz[(size_t)(t0-3)*(2*ED_)+e] : 0.f;
  float x1 = (t0 >= 2) ? xz[(size_t)(t0-2)*(2*ED_)+e] : 0.f;
  float x2 = (t0 >= 1) ? xz[(size_t)(t0-1)*(2*ED_)+e] : 0.f;
  #pragma unroll
  for (int j = 0; j < 8; ++j) {
    const float x3 = xz[(size_t)(t0+j)*(2*ED_)+e];
    const float uv = silu_f(b + w0*x0 + w1*x1 + w2*x2 + w3*x3);
    u[(size_t)(t0+j)*ED_+e] = uv;
    ub[(size_t)(t0+j)*ED_+e] = (__bf16)uv;
    x0 = x1; x1 = x2; x2 = x3;
  }
}

// ---- chunked selective scan ----
__global__ __launch_bounds__(256) void scan_phase1(
    const float* __restrict__ delta, const float* __restrict__ u,
    const float* __restrict__ xdbl, const float* __restrict__ A_log,
    float* __restrict__ hend, float* __restrict__ Pend)
{
  __shared__ float dl[16][8], ul[16][8];
  __shared__ float bl[16][32];
  const int tid = threadIdx.x;
  const int n = tid & 31;
  const int c = tid >> 5;
  const int e0 = blockIdx.x * 8;
  const int e = e0 + c;
  const int ch = blockIdx.y;
  const float a = -expf(A_log[e * NST + n]);
  float h = 0.f, S = 0.f;
  const int t0 = ch * CHUNK;
  const int s_t = (tid & 127) >> 3, s_e = tid & 7;
  const int b_c = (tid & 7) * 4;

  float rg_a = 0.f;
  float4 rg_b;
  if (tid < 128) {
    rg_a = delta[(size_t)(t0 + s_t) * ED_ + e0 + s_e];
    rg_b = *reinterpret_cast<const float4*>(&xdbl[(size_t)(t0 + s_t) * 128 + 64 + b_c]);
  } else {
    rg_a = u[(size_t)(t0 + s_t) * ED_ + e0 + s_e];
  }

  for (int tb = 0; tb < CHUNK; tb += 16) {
    if (tid < 128) {
      dl[s_t][s_e] = rg_a;
      *reinterpret_cast<float4*>(&bl[s_t][b_c]) = rg_b;
    } else {
      ul[s_t][s_e] = rg_a;
    }
    __syncthreads();
    if (tb + 16 < CHUNK) {
      const int t = t0 + tb + 16 + s_t;
      if (tid < 128) {
        rg_a = delta[(size_t)t * ED_ + e0 + s_e];
        rg_b = *reinterpret_cast<const float4*>(&xdbl[(size_t)t * 128 + 64 + b_c]);
      } else {
        rg_a = u[(size_t)t * ED_ + e0 + s_e];
      }
    }
    #pragma unroll
    for (int j = 0; j < 16; ++j) {
      const float sd = dl[j][c];
      const float uv = ul[j][c];
      const float Bv = bl[j][n];
      h = fmaf(__expf(sd * a), h, sd * uv * Bv);
      S += sd;
    }
    __syncthreads();
  }
  const int idx = ch * (ED_ * NST) + blockIdx.x * 256 + tid;
  hend[idx] = h;
  Pend[idx] = __expf(a * S);
}

// phase 3: 2 chunks per block (grid.y = NCH/2) -> 1024 blocks <= 1792 residency,
// zero scheduling tail. Per-chunk: inline h_in combine + pipelined LDS tiles.
__global__ __launch_bounds__(256, 7) void scan_phase3(
    const float* __restrict__ delta, const float* __restrict__ u,
    const float* __restrict__ xdbl, const float* __restrict__ A_log,
    const float* __restrict__ hend, const float* __restrict__ Pend,
    const float* __restrict__ Dp,
    const float* __restrict__ xz, __bf16* __restrict__ y)
{
  __shared__ float p_lds[8][16][33];
  __shared__ float dl[16][8], ul[16][8], zl[16][8];
  __shared__ float bc[16][64];
  const int tid = threadIdx.x;
  const int n = tid & 31;
  const int c = tid >> 5;
  const int e0 = blockIdx.x * 8;
  const int e = e0 + c;
  const float a = -expf(A_log[e * NST + n]);
  const float dp = Dp[e];

  const int r = n & 15, half = n >> 4;
  const int s_t  = (tid & 127) >> 3;
  const int s_e  = tid & 7;
  const int b_t  = tid >> 4;
  const int b_c  = (tid & 15) * 4;
  const int sidx = blockIdx.x * 256 + tid;

  #pragma unroll
  for (int ci = 0; ci < 2; ++ci) {
    const int ch = blockIdx.y * 2 + ci;
    // inline chunk combine: h_in for chunk ch
    float h = 0.f;
    for (int cc = 0; cc < ch; ++cc) {
      const int off = cc * (ED_ * NST) + sidx;
      h = fmaf(Pend[off], h, hend[off]);
    }

    const int t0 = ch * CHUNK;
    // prologue: load tile 0 into registers
    float rg_a = 0.f, rg_z = 0.f;
    float4 rg_bc;
    {
      const int t = t0 + s_t;
      if (tid < 128) {
        rg_a = delta[(size_t)t * ED_ + e0 + s_e];
        rg_z = xz[(size_t)t * (2*ED_) + ED_ + e0 + s_e];
      } else {
        rg_a = u[(size_t)t * ED_ + e0 + s_e];
      }
      rg_bc = *reinterpret_cast<const float4*>(&xdbl[(size_t)(t0 + b_t) * 128 + 64 + b_c]);
    }

    for (int tb = 0; tb < CHUNK; tb += 16) {
      if (tid < 128) { dl[s_t][s_e] = rg_a; zl[s_t][s_e] = rg_z; }
      else          { ul[s_t][s_e] = rg_a; }
      *reinterpret_cast<float4*>(&bc[b_t][b_c]) = rg_bc;
      __syncthreads();
      if (tb + 16 < CHUNK) {
        const int t = t0 + tb + 16 + s_t;
        if (tid < 128) {
          rg_a = delta[(size_t)t * ED_ + e0 + s_e];
          rg_z = xz[(size_t)t * (2*ED_) + ED_ + e0 + s_e];
        } else {
          rg_a = u[(size_t)t * ED_ + e0 + s_e];
        }
        rg_bc = *reinterpret_cast<const float4*>(&xdbl[(size_t)(t0 + tb + 16 + b_t) * 128 + 64 + b_c]);
      }
      #pragma unroll
      for (int j = 0; j < 16; ++j) {
        const float sd = dl[j][c];
        const float uv = ul[j][c];
        const float Bv = bc[j][n];
        const float Cv = bc[j][32 + n];
        const float dA = __expf(sd * a);
        h = fmaf(dA, h, sd * uv * Bv);
        p_lds[c][j][n] = h * Cv;
      }
      __syncthreads();
      float s = 0.f;
      #pragma unroll
      for (int k = 0; k < 16; ++k) s += p_lds[c][r][half * 16 + k];
      s += __shfl_xor(s, 16, 64);
      if (half == 0) {
        const float uvt = ul[r][c];
        const float zv  = zl[r][c];
        y[(size_t)(t0 + tb + r) * ED_ + e] = (__bf16)((s + uvt * dp) * silu_f(zv));
      }
      __syncthreads();
    }
  }
}

// column-mean partials (coalesced)
__global__ __launch_bounds__(256) void colmean_part_k(
    const float* __restrict__ hf, float* __restrict__ part)
{
  const int d = blockIdx.x * 256 + threadIdx.x;
  const int tc = blockIdx.y;
  float s = 0.f;
  #pragma unroll 8
  for (int j = 0; j < 32; ++j) s += hf[(size_t)(tc * 32 + j) * D_ + d];
  part[tc * D_ + d] = s;
}

// fused finalize + state projection
__global__ __launch_bounds__(256) void state_fused_k(
    const float* __restrict__ part, const float* __restrict__ spw,
    const float* __restrict__ spb, float* __restrict__ out)
{
  __shared__ float red[4];
  const int nidx = blockIdx.x;
  const int tid = threadIdx.x;
  float s = 0.f;
  for (int d = tid; d < D_; d += 256) {
    float cm = 0.f;
    #pragma unroll
    for (int c = 0; c < 32; ++c) cm += part[c * D_ + d];
    s += cm * (1.f / L_) * spw[(size_t)nidx * D_ + d];
  }
  #pragma unroll
  for (int off = 32; off; off >>= 1) s += __shfl_down(s, off, 64);
  if ((tid & 63) == 0) red[tid >> 6] = s;
  __syncthreads();
  if (tid == 0) out[nidx] = red[0] + red[1] + red[2] + red[3] + spb[nidx];
}

extern "C" void kernel_launch(void* const* d_in, const int* in_sizes, int n_in,
                              void* d_out, int out_size, void* d_ws, size_t ws_size,
                              hipStream_t stream) {
  const float* x        = (const float*)d_in[0];
  const float* Wi       = (const float*)d_in[1];
  const float* bi       = (const float*)d_in[2];
  const float* ln_g     = (const float*)d_in[3];
  const float* ln_b     = (const float*)d_in[4];
  const float* in_w     = (const float*)d_in[5];
  const float* conv_w   = (const float*)d_in[6];
  const float* conv_b   = (const float*)d_in[7];
  const float* xproj_w  = (const float*)d_in[8];
  const float* dtproj_w = (const float*)d_in[9];
  const float* dtproj_b = (const float*)d_in[10];
  const float* A_log    = (const float*)d_in[11];
  const float* Dp       = (const float*)d_in[12];
  const float* out_w    = (const float*)d_in[13];
  const float* fn_g     = (const float*)d_in[14];
  const float* fn_b     = (const float*)d_in[15];
  const float* sp_w     = (const float*)d_in[16];
  const float* sp_b     = (const float*)d_in[17];
  float* out  = (float*)d_out;
  float* ws_f = (float*)d_ws;

  float* h_buf  = ws_f;                // 1048576
  float* xz     = ws_f + 1048576;      // 4194304
  float* u_buf  = ws_f + 5242880;      // 2097152
  float* xdbl   = ws_f + 7340032;      // 131072
  float* delta  = ws_f + 7471104;      // 2097152 (also xproj partials)
  float* hend   = ws_f + 9568256;      // 524288
  float* pend   = ws_f + 10092544;     // 524288
  __bf16* nbf   = (__bf16*)(ws_f + 10617856);  // 1M bf16
  __bf16* ybf   = (__bf16*)(ws_f + 11142144);  // 2M bf16
  __bf16* wbf   = (__bf16*)(ws_f + 12190720);  // 8M bf16 (in_w)
  __bf16* xdblbf= (__bf16*)(ws_f + 16385024);  // 128K bf16
  __bf16* dtwbf = (__bf16*)(ws_f + 16450560);  // 128K bf16
  __bf16* ubf   = (__bf16*)(ws_f + 16516096);  // 2M bf16
  __bf16* xpbf  = (__bf16*)(ws_f + 17564672);  // 256K bf16
  __bf16* owbf  = (__bf16*)(ws_f + 17695744);  // 2M bf16 (out_w)
  float* skmf   = u_buf;               // MFMA split-K partials overlay (Wi/out)
  float* skxp   = delta;               // xproj split-K partials overlay
  float* cmpart = hend;                // colmean partials overlay

  const dim3 blk(256);

  // prologue: convert x + Wi in one launch; Wi GEMM split-K=4
  f2bf4_k<<<1024, blk, 0, stream>>>(x, nbf, L_*D_, Wi, wbf, D_*D_,
                                    x, nbf, 0, x, nbf, 0);
  gemm_mfma_sk<<<dim3(D_/128, L_/128, ZSPL), blk, 0, stream>>>(
      nbf, wbf, skmf, L_, D_, D_, D_/ZSPL);
  mfma_sk_reduce<<<dim3(L_*D_/4/256), blk, 0, stream>>>(
      skmf, bi, h_buf, nullptr, L_*D_, D_, ZSPL, 4);

  for (int i = 0; i < NB_; ++i) {
    f2bf4_k<<<3264, blk, 0, stream>>>(
        in_w    + (size_t)i*2*ED_*D_, wbf,   2*ED_*D_,
        xproj_w + (size_t)i*128*ED_,  xpbf,  128*ED_,
        dtproj_w+ (size_t)i*ED_*DTR_, dtwbf, ED_*DTR_,
        out_w   + (size_t)i*D_*ED_,   owbf,  D_*ED_);
    layernorm_bf_k<<<L_, blk, 0, stream>>>(h_buf, ln_g + i*D_, ln_b + i*D_, nbf);
    // xz = normed @ in_w^T
    gemm_mfma<<<dim3(2*ED_/128, L_/128), blk, 0, stream>>>(
        nbf, D_, wbf, D_, nullptr, xz, 2*ED_, D_, 0);
    conv_silu_k<<<dim3(ED_/256, L_/8), blk, 0, stream>>>(
        xz, conv_w + (size_t)i*ED_*KCONV, conv_b + (size_t)i*ED_, u_buf, ubf);
    // x_dbl = u @ xproj^T  (bf16 MFMA split-K=16)
    gemm_mfma_sk<<<dim3(1, L_/128, XPZ), blk, 0, stream>>>(
        ubf, xpbf, skxp, L_, 128, ED_, ED_/XPZ);
    mfma_sk_reduce<<<dim3(L_*128/4/256), blk, 0, stream>>>(
        skxp, nullptr, xdbl, xdblbf, L_*128, 128, XPZ, 8);
    // delta = softplus(dt @ dtproj^T + b)  (bf16 MFMA, K=64)
    gemm_mfma<<<dim3(ED_/128, L_/128), blk, 0, stream>>>(
        xdblbf, 128, dtwbf, DTR_, dtproj_b + (size_t)i*ED_, delta, ED_, DTR_, 2 | 4);
    // chunked scan (phase3: 2 chunks/block -> no scheduling tail)
    scan_phase1<<<dim3(ED_/8, NCH), blk, 0, stream>>>(
        delta, u_buf, xdbl, A_log + (size_t)i*ED_*NST, hend, pend);
    scan_phase3<<<dim3(ED_/8, NCH/2), blk, 0, stream>>>(
        delta, u_buf, xdbl, A_log + (size_t)i*ED_*NST, hend, pend,
        Dp + (size_t)i*ED_, xz, ybf);
    // h += y @ out_w^T   (bf16 MFMA, split-K=4)
    gemm_mfma_sk<<<dim3(D_/128, L_/128, ZSPL), blk, 0, stream>>>(
        ybf, owbf, skmf, L_, D_, ED_, ED_/ZSPL);
    mfma_sk_reduce<<<dim3(L_*D_/4/256), blk, 0, stream>>>(
        skmf, nullptr, h_buf, nullptr, L_*D_, D_, ZSPL, 1);
  }

  layernorm_k<<<L_, blk, 0, stream>>>(h_buf, fn_g, fn_b, out);
  colmean_part_k<<<dim3(D_/256, 32), blk, 0, stream>>>(out, cmpart);
  state_fused_k<<<NST, blk, 0, stream>>>(cmpart, sp_w, sp_b, out + (size_t)L_*D_);
}

// Round 16
// 659.351 us; speedup vs baseline: 1.0487x; 1.0213x over previous
//
#include <hip/hip_runtime.h>
#include <math.h>

#define D_    1024
#define ED_   2048
#define NST   32
#define KCONV 4
#define DTR_  64
#define L_    1024
#define NB_   4
#define NCH   8
#define CHUNK (L_ / NCH)
#define ZSPL  4
#define XPZ   16

typedef __bf16 bf16_8 __attribute__((ext_vector_type(8)));
typedef __bf16 bf16_4 __attribute__((ext_vector_type(4)));
typedef float  f32x4  __attribute__((ext_vector_type(4)));

__device__ __forceinline__ float softplus_f(float x) {
  return x > 20.f ? x : log1pf(expf(x));
}
__device__ __forceinline__ float silu_f(float x) {
  return x / (1.f + expf(-x));
}

// XCD-aware bijective remap (nwg % 8 == 0 for all our GEMM grids)
__device__ __forceinline__ int xcd_swz(int lin, int nwg) {
  const int q = nwg >> 3;
  return (lin & 7) * q + (lin >> 3);
}

// segmented fp32 -> bf16 (each count multiple of 8)
__global__ __launch_bounds__(256) void f2bf4_k(
    const float* __restrict__ i0, __bf16* __restrict__ o0, int n0,
    const float* __restrict__ i1, __bf16* __restrict__ o1, int n1,
    const float* __restrict__ i2, __bf16* __restrict__ o2, int n2,
    const float* __restrict__ i3, __bf16* __restrict__ o3, int n3)
{
  int gid = blockIdx.x * 256 + threadIdx.x;
  const int u0 = n0 >> 3, u1 = n1 >> 3, u2 = n2 >> 3, u3 = n3 >> 3;
  const float* in; __bf16* out;
  if (gid < u0) { in = i0; out = o0; }
  else if ((gid -= u0) < u1) { in = i1; out = o1; }
  else if ((gid -= u1) < u2) { in = i2; out = o2; }
  else if ((gid -= u2) < u3) { in = i3; out = o3; }
  else return;
  const int i = gid * 8;
  const float4 a = *reinterpret_cast<const float4*>(in + i);
  const float4 b = *reinterpret_cast<const float4*>(in + i + 4);
  bf16_8 v;
  v[0]=(__bf16)a.x; v[1]=(__bf16)a.y; v[2]=(__bf16)a.z; v[3]=(__bf16)a.w;
  v[4]=(__bf16)b.x; v[5]=(__bf16)b.y; v[6]=(__bf16)b.z; v[7]=(__bf16)b.w;
  *reinterpret_cast<bf16_8*>(out + i) = v;
}

// ---- MFMA bf16 GEMM (128x128, BK=64, XOR-swizzled LDS, XCD-swizzled grid) ----
// flags: 1=accumulate, 2=softplus, 4=bias
__global__ __launch_bounds__(256) void gemm_mfma(
    const __bf16* __restrict__ A, int lda,
    const __bf16* __restrict__ W, int ldw,
    const float* __restrict__ bias, float* __restrict__ C, int ldc,
    int K, int flags)
{
  __shared__ __bf16 As[128 * 64];
  __shared__ __bf16 Ws[128 * 64];
  const int tid  = threadIdx.x;
  const int lane = tid & 63;
  const int w    = tid >> 6;
  const int wr   = w >> 1, wc = w & 1;
  const int nwg  = gridDim.x * gridDim.y;
  const int swz  = xcd_swz(blockIdx.y * gridDim.x + blockIdx.x, nwg);
  const int bx   = swz % gridDim.x, by = swz / gridDim.x;
  const int row0 = by * 128, col0 = bx * 128;

  f32x4 acc[4][4] = {};

  for (int k0 = 0; k0 < K; k0 += 64) {
    #pragma unroll
    for (int j = 0; j < 4; ++j) {
      const int inst = w * 4 + j;
      const int row  = inst * 8 + (lane >> 3);
      const int lu   = (lane & 7) ^ (row & 7);
      __builtin_amdgcn_global_load_lds(
          (const __attribute__((address_space(1))) void*)(A + (size_t)(row0 + row) * lda + k0 + lu * 8),
          (__attribute__((address_space(3))) void*)(&As[inst * 512]), 16, 0, 0);
      __builtin_amdgcn_global_load_lds(
          (const __attribute__((address_space(1))) void*)(W + (size_t)(col0 + row) * ldw + k0 + lu * 8),
          (__attribute__((address_space(3))) void*)(&Ws[inst * 512]), 16, 0, 0);
    }
    __syncthreads();
    const int r16 = lane & 15;
    const int uq  = lane >> 4;
    #pragma unroll
    for (int ks = 0; ks < 2; ++ks) {
      bf16_8 af[4], bfr[4];
      #pragma unroll
      for (int m = 0; m < 4; ++m) {
        const int row = wr * 64 + m * 16 + r16;
        const int pu  = (ks * 4 + uq) ^ (row & 7);
        af[m] = *reinterpret_cast<const bf16_8*>(&As[row * 64 + pu * 8]);
      }
      #pragma unroll
      for (int n = 0; n < 4; ++n) {
        const int row = wc * 64 + n * 16 + r16;
        const int pu  = (ks * 4 + uq) ^ (row & 7);
        bfr[n] = *reinterpret_cast<const bf16_8*>(&Ws[row * 64 + pu * 8]);
      }
      #pragma unroll
      for (int m = 0; m < 4; ++m)
        #pragma unroll
        for (int n = 0; n < 4; ++n)
          acc[m][n] = __builtin_amdgcn_mfma_f32_16x16x32_bf16(af[m], bfr[n], acc[m][n], 0, 0, 0);
    }
    __syncthreads();
  }

  const int crow = (lane >> 4) * 4;
  const int ccol = lane & 15;
  #pragma unroll
  for (int m = 0; m < 4; ++m)
    #pragma unroll
    for (int n = 0; n < 4; ++n) {
      const int col = col0 + wc * 64 + n * 16 + ccol;
      const float bv = (flags & 4) ? bias[col] : 0.f;
      #pragma unroll
      for (int r = 0; r < 4; ++r) {
        const int row = row0 + wr * 64 + m * 16 + crow + r;
        float* cp = C + (size_t)row * ldc + col;
        float v = acc[m][n][r] + bv;
        if (flags & 2) v = softplus_f(v);
        if (flags & 1) v += *cp;
        *cp = v;
      }
    }
}

// split-K MFMA GEMM (lda=ldw=K)
__global__ __launch_bounds__(256) void gemm_mfma_sk(
    const __bf16* __restrict__ A, const __bf16* __restrict__ W,
    float* __restrict__ partials, int M, int N, int K, int Kc)
{
  __shared__ __bf16 As[128 * 64];
  __shared__ __bf16 Ws[128 * 64];
  const int tid  = threadIdx.x;
  const int lane = tid & 63;
  const int w    = tid >> 6;
  const int wr   = w >> 1, wc = w & 1;
  const int nwg  = gridDim.x * gridDim.y * gridDim.z;
  const int lin  = (blockIdx.z * gridDim.y + blockIdx.y) * gridDim.x + blockIdx.x;
  const int swz  = xcd_swz(lin, nwg);
  const int bx   = swz % gridDim.x;
  const int tmp  = swz / gridDim.x;
  const int by   = tmp % gridDim.y, bz = tmp / gridDim.y;
  const int row0 = by * 128, col0 = bx * 128;
  const int kbase = bz * Kc;

  f32x4 acc[4][4] = {};

  for (int k0 = kbase; k0 < kbase + Kc; k0 += 64) {
    #pragma unroll
    for (int j = 0; j < 4; ++j) {
      const int inst = w * 4 + j;
      const int row  = inst * 8 + (lane >> 3);
      const int lu   = (lane & 7) ^ (row & 7);
      __builtin_amdgcn_global_load_lds(
          (const __attribute__((address_space(1))) void*)(A + (size_t)(row0 + row) * K + k0 + lu * 8),
          (__attribute__((address_space(3))) void*)(&As[inst * 512]), 16, 0, 0);
      __builtin_amdgcn_global_load_lds(
          (const __attribute__((address_space(1))) void*)(W + (size_t)(col0 + row) * K + k0 + lu * 8),
          (__attribute__((address_space(3))) void*)(&Ws[inst * 512]), 16, 0, 0);
    }
    __syncthreads();
    const int r16 = lane & 15;
    const int uq  = lane >> 4;
    #pragma unroll
    for (int ks = 0; ks < 2; ++ks) {
      bf16_8 af[4], bfr[4];
      #pragma unroll
      for (int m = 0; m < 4; ++m) {
        const int row = wr * 64 + m * 16 + r16;
        const int pu  = (ks * 4 + uq) ^ (row & 7);
        af[m] = *reinterpret_cast<const bf16_8*>(&As[row * 64 + pu * 8]);
      }
      #pragma unroll
      for (int n = 0; n < 4; ++n) {
        const int row = wc * 64 + n * 16 + r16;
        const int pu  = (ks * 4 + uq) ^ (row & 7);
        bfr[n] = *reinterpret_cast<const bf16_8*>(&Ws[row * 64 + pu * 8]);
      }
      #pragma unroll
      for (int m = 0; m < 4; ++m)
        #pragma unroll
        for (int n = 0; n < 4; ++n)
          acc[m][n] = __builtin_amdgcn_mfma_f32_16x16x32_bf16(af[m], bfr[n], acc[m][n], 0, 0, 0);
    }
    __syncthreads();
  }

  float* base = partials + (size_t)bz * M * N;
  const int crow = (lane >> 4) * 4;
  const int ccol = lane & 15;
  #pragma unroll
  for (int m = 0; m < 4; ++m)
    #pragma unroll
    for (int n = 0; n < 4; ++n) {
      const int col = col0 + wc * 64 + n * 16 + ccol;
      #pragma unroll
      for (int r = 0; r < 4; ++r) {
        const int row = row0 + wr * 64 + m * 16 + crow + r;
        base[(size_t)row * N + col] = acc[m][n][r];
      }
    }
}

// reduce nz partials -> C; flags: 1=acc into C, 4=bias(per col), 8=emit bf16 copy
__global__ __launch_bounds__(256) void mfma_sk_reduce(
    const float* __restrict__ partials, const float* __restrict__ bias,
    float* __restrict__ C, __bf16* __restrict__ Cbf,
    int elems, int ncols, int nz, int flags)
{
  const int i = (blockIdx.x * 256 + threadIdx.x) * 4;
  if (i >= elems) return;
  float4 s = *reinterpret_cast<const float4*>(partials + i);
  for (int z = 1; z < nz; ++z) {
    const float4 p = *reinterpret_cast<const float4*>(partials + (size_t)z * elems + i);
    s.x += p.x; s.y += p.y; s.z += p.z; s.w += p.w;
  }
  if (flags & 4) {
    const float4 bv = *reinterpret_cast<const float4*>(bias + (i % ncols));
    s.x += bv.x; s.y += bv.y; s.z += bv.z; s.w += bv.w;
  }
  if (flags & 1) {
    const float4 ov = *reinterpret_cast<const float4*>(C + i);
    s.x += ov.x; s.y += ov.y; s.z += ov.z; s.w += ov.w;
  }
  *reinterpret_cast<float4*>(C + i) = s;
  if (flags & 8) {
    bf16_4 b;
    b[0]=(__bf16)s.x; b[1]=(__bf16)s.y; b[2]=(__bf16)s.z; b[3]=(__bf16)s.w;
    *reinterpret_cast<bf16_4*>(Cbf + i) = b;
  }
}

// layernorm, fp32 out (final LN)
__global__ __launch_bounds__(256) void layernorm_k(
    const float* __restrict__ x, const float* __restrict__ g,
    const float* __restrict__ b, float* __restrict__ out)
{
  __shared__ float red[8];
  const int row = blockIdx.x;
  const int tid = threadIdx.x;
  const float* xr = x + (size_t)row * D_;
  float4 v = *reinterpret_cast<const float4*>(xr + tid * 4);
  float s = v.x + v.y + v.z + v.w;
  #pragma unroll
  for (int off = 32; off; off >>= 1) s += __shfl_down(s, off, 64);
  if ((tid & 63) == 0) red[tid >> 6] = s;
  __syncthreads();
  const float m = (red[0] + red[1] + red[2] + red[3]) * (1.f / D_);
  float dx0 = v.x - m, dx1 = v.y - m, dx2 = v.z - m, dx3 = v.w - m;
  float ss = dx0*dx0 + dx1*dx1 + dx2*dx2 + dx3*dx3;
  #pragma unroll
  for (int off = 32; off; off >>= 1) ss += __shfl_down(ss, off, 64);
  if ((tid & 63) == 0) red[4 + (tid >> 6)] = ss;
  __syncthreads();
  const float var = (red[4] + red[5] + red[6] + red[7]) * (1.f / D_);
  const float rs = rsqrtf(var + 1e-5f);
  const int c = tid * 4;
  const float4 gv = *reinterpret_cast<const float4*>(g + c);
  const float4 bv = *reinterpret_cast<const float4*>(b + c);
  float4 o;
  o.x = dx0 * rs * gv.x + bv.x;
  o.y = dx1 * rs * gv.y + bv.y;
  o.z = dx2 * rs * gv.z + bv.z;
  o.w = dx3 * rs * gv.w + bv.w;
  *reinterpret_cast<float4*>(out + (size_t)row * D_ + c) = o;
}

// layernorm with bf16 out
__global__ __launch_bounds__(256) void layernorm_bf_k(
    const float* __restrict__ x, const float* __restrict__ g,
    const float* __restrict__ b, __bf16* __restrict__ out)
{
  __shared__ float red[8];
  const int row = blockIdx.x;
  const int tid = threadIdx.x;
  const float* xr = x + (size_t)row * D_;
  float4 v = *reinterpret_cast<const float4*>(xr + tid * 4);
  float s = v.x + v.y + v.z + v.w;
  #pragma unroll
  for (int off = 32; off; off >>= 1) s += __shfl_down(s, off, 64);
  if ((tid & 63) == 0) red[tid >> 6] = s;
  __syncthreads();
  const float m = (red[0] + red[1] + red[2] + red[3]) * (1.f / D_);
  float dx0 = v.x - m, dx1 = v.y - m, dx2 = v.z - m, dx3 = v.w - m;
  float ss = dx0*dx0 + dx1*dx1 + dx2*dx2 + dx3*dx3;
  #pragma unroll
  for (int off = 32; off; off >>= 1) ss += __shfl_down(ss, off, 64);
  if ((tid & 63) == 0) red[4 + (tid >> 6)] = ss;
  __syncthreads();
  const float var = (red[4] + red[5] + red[6] + red[7]) * (1.f / D_);
  const float rs = rsqrtf(var + 1e-5f);
  const int c = tid * 4;
  const float4 gv = *reinterpret_cast<const float4*>(g + c);
  const float4 bv = *reinterpret_cast<const float4*>(b + c);
  bf16_4 o;
  o[0] = (__bf16)(dx0 * rs * gv.x + bv.x);
  o[1] = (__bf16)(dx1 * rs * gv.y + bv.y);
  o[2] = (__bf16)(dx2 * rs * gv.z + bv.z);
  o[3] = (__bf16)(dx3 * rs * gv.w + bv.w);
  *reinterpret_cast<bf16_4*>(out + (size_t)row * D_ + c) = o;
}

// depthwise causal conv K=4 + bias + silu; 8 timesteps/thread; fp32 + bf16 out
__global__ __launch_bounds__(256) void conv_silu_k(
    const float* __restrict__ xz, const float* __restrict__ cw,
    const float* __restrict__ cb, float* __restrict__ u, __bf16* __restrict__ ub)
{
  const int e = blockIdx.x * 256 + threadIdx.x;
  const int t0 = blockIdx.y * 8;
  const float w0 = cw[e*4+0], w1 = cw[e*4+1], w2 = cw[e*4+2], w3 = cw[e*4+3];
  const float b = cb[e];
  float x0 = (t0 >= 3) ? xz[(size_t)(t0-3)*(2*ED_)+e] : 0.f;
  float x1 = (t0 >= 2) ? xz[(size_t)(t0-2)*(2*ED_)+e] : 0.f;
  float x2 = (t0 >= 1) ? xz[(size_t)(t0-1)*(2*ED_)+e] : 0.f;
  #pragma unroll
  for (int j = 0; j < 8; ++j) {
    const float x3 = xz[(size_t)(t0+j)*(2*ED_)+e];
    const float uv = silu_f(b + w0*x0 + w1*x1 + w2*x2 + w3*x3);
    u[(size_t)(t0+j)*ED_+e] = uv;
    ub[(size_t)(t0+j)*ED_+e] = (__bf16)uv;
    x0 = x1; x1 = x2; x2 = x3;
  }
}

// ---- chunked selective scan ----
// phase 1: (delta,u) packed float2 in LDS -> 2 ds_read/step
__global__ __launch_bounds__(256) void scan_phase1(
    const float* __restrict__ delta, const float* __restrict__ u,
    const float* __restrict__ xdbl, const float* __restrict__ A_log,
    float* __restrict__ hend, float* __restrict__ Pend)
{
  __shared__ float du[16][8][2];
  __shared__ float bl[16][32];
  const int tid = threadIdx.x;
  const int n = tid & 31;
  const int c = tid >> 5;
  const int e0 = blockIdx.x * 8;
  const int e = e0 + c;
  const int ch = blockIdx.y;
  const float a = -expf(A_log[e * NST + n]);
  float h = 0.f, S = 0.f;
  const int t0 = ch * CHUNK;
  const int s_t = (tid & 127) >> 3, s_e = tid & 7;
  const int b_c = (tid & 7) * 4;

  float rg_a = 0.f;
  float4 rg_b;
  if (tid < 128) {
    rg_a = delta[(size_t)(t0 + s_t) * ED_ + e0 + s_e];
    rg_b = *reinterpret_cast<const float4*>(&xdbl[(size_t)(t0 + s_t) * 128 + 64 + b_c]);
  } else {
    rg_a = u[(size_t)(t0 + s_t) * ED_ + e0 + s_e];
  }

  for (int tb = 0; tb < CHUNK; tb += 16) {
    if (tid < 128) {
      du[s_t][s_e][0] = rg_a;
      *reinterpret_cast<float4*>(&bl[s_t][b_c]) = rg_b;
    } else {
      du[s_t][s_e][1] = rg_a;
    }
    __syncthreads();
    if (tb + 16 < CHUNK) {
      const int t = t0 + tb + 16 + s_t;
      if (tid < 128) {
        rg_a = delta[(size_t)t * ED_ + e0 + s_e];
        rg_b = *reinterpret_cast<const float4*>(&xdbl[(size_t)t * 128 + 64 + b_c]);
      } else {
        rg_a = u[(size_t)t * ED_ + e0 + s_e];
      }
    }
    #pragma unroll
    for (int j = 0; j < 16; ++j) {
      const float2 duv = *reinterpret_cast<const float2*>(&du[j][c][0]);
      const float Bv = bl[j][n];
      h = fmaf(__expf(duv.x * a), h, duv.x * duv.y * Bv);
      S += duv.x;
    }
    __syncthreads();
  }
  const int idx = ch * (ED_ * NST) + blockIdx.x * 256 + tid;
  hend[idx] = h;
  Pend[idx] = __expf(a * S);
}

// phase 3: inline combine + pipelined tiles; (delta,u) and (B,C) packed -> 2 ds_read/step
__global__ __launch_bounds__(256, 7) void scan_phase3(
    const float* __restrict__ delta, const float* __restrict__ u,
    const float* __restrict__ xdbl, const float* __restrict__ A_log,
    const float* __restrict__ hend, const float* __restrict__ Pend,
    const float* __restrict__ Dp,
    const float* __restrict__ xz, __bf16* __restrict__ y)
{
  __shared__ float p_lds[8][16][33];      // 16896 B
  __shared__ float du[16][8][2], zl[16][8];  // 1536 B
  __shared__ float bcp[16][32][2];        // 4096 B
  const int tid = threadIdx.x;
  const int n = tid & 31;
  const int c = tid >> 5;
  const int e0 = blockIdx.x * 8;
  const int e = e0 + c;
  const int ch = blockIdx.y;
  const float a = -expf(A_log[e * NST + n]);
  const float dp = Dp[e];

  float h = 0.f;
  {
    const int sidx = blockIdx.x * 256 + tid;
    for (int cc = 0; cc < ch; ++cc) {
      const int off = cc * (ED_ * NST) + sidx;
      h = fmaf(Pend[off], h, hend[off]);
    }
  }

  const int t0 = ch * CHUNK;
  const int r = n & 15, half = n >> 4;
  const int s_t  = (tid & 127) >> 3;
  const int s_e  = tid & 7;
  const int b_t  = tid >> 4;
  const int b_c  = (tid & 15) * 4;
  const int b_isC = (b_c >= 32);
  const int b_n0  = b_c & 31;

  float rg_a = 0.f, rg_z = 0.f;
  float4 rg_bc;
  {
    const int t = t0 + s_t;
    if (tid < 128) {
      rg_a = delta[(size_t)t * ED_ + e0 + s_e];
      rg_z = xz[(size_t)t * (2*ED_) + ED_ + e0 + s_e];
    } else {
      rg_a = u[(size_t)t * ED_ + e0 + s_e];
    }
    rg_bc = *reinterpret_cast<const float4*>(&xdbl[(size_t)(t0 + b_t) * 128 + 64 + b_c]);
  }

  for (int tb = 0; tb < CHUNK; tb += 16) {
    if (tid < 128) { du[s_t][s_e][0] = rg_a; zl[s_t][s_e] = rg_z; }
    else          { du[s_t][s_e][1] = rg_a; }
    // interleaved (B,C) store: 4 scalar writes
    bcp[b_t][b_n0 + 0][b_isC] = rg_bc.x;
    bcp[b_t][b_n0 + 1][b_isC] = rg_bc.y;
    bcp[b_t][b_n0 + 2][b_isC] = rg_bc.z;
    bcp[b_t][b_n0 + 3][b_isC] = rg_bc.w;
    __syncthreads();
    if (tb + 16 < CHUNK) {
      const int t = t0 + tb + 16 + s_t;
      if (tid < 128) {
        rg_a = delta[(size_t)t * ED_ + e0 + s_e];
        rg_z = xz[(size_t)t * (2*ED_) + ED_ + e0 + s_e];
      } else {
        rg_a = u[(size_t)t * ED_ + e0 + s_e];
      }
      rg_bc = *reinterpret_cast<const float4*>(&xdbl[(size_t)(t0 + tb + 16 + b_t) * 128 + 64 + b_c]);
    }
    #pragma unroll
    for (int j = 0; j < 16; ++j) {
      const float2 duv = *reinterpret_cast<const float2*>(&du[j][c][0]);
      const float2 BC  = *reinterpret_cast<const float2*>(&bcp[j][n][0]);
      const float dA = __expf(duv.x * a);
      h = fmaf(dA, h, duv.x * duv.y * BC.x);
      p_lds[c][j][n] = h * BC.y;
    }
    // hoist epilogue operands before reduce barrier
    const float uvt = du[r][c][1];
    const float zv  = zl[r][c];
    __syncthreads();
    float s = 0.f;
    #pragma unroll
    for (int k = 0; k < 16; ++k) s += p_lds[c][r][half * 16 + k];
    s += __shfl_xor(s, 16, 64);
    if (half == 0) {
      y[(size_t)(t0 + tb + r) * ED_ + e] = (__bf16)((s + uvt * dp) * silu_f(zv));
    }
    __syncthreads();
  }
}

// column-mean partials (coalesced)
__global__ __launch_bounds__(256) void colmean_part_k(
    const float* __restrict__ hf, float* __restrict__ part)
{
  const int d = blockIdx.x * 256 + threadIdx.x;
  const int tc = blockIdx.y;
  float s = 0.f;
  #pragma unroll 8
  for (int j = 0; j < 32; ++j) s += hf[(size_t)(tc * 32 + j) * D_ + d];
  part[tc * D_ + d] = s;
}

// fused finalize + state projection
__global__ __launch_bounds__(256) void state_fused_k(
    const float* __restrict__ part, const float* __restrict__ spw,
    const float* __restrict__ spb, float* __restrict__ out)
{
  __shared__ float red[4];
  const int nidx = blockIdx.x;
  const int tid = threadIdx.x;
  float s = 0.f;
  for (int d = tid; d < D_; d += 256) {
    float cm = 0.f;
    #pragma unroll
    for (int c = 0; c < 32; ++c) cm += part[c * D_ + d];
    s += cm * (1.f / L_) * spw[(size_t)nidx * D_ + d];
  }
  #pragma unroll
  for (int off = 32; off; off >>= 1) s += __shfl_down(s, off, 64);
  if ((tid & 63) == 0) red[tid >> 6] = s;
  __syncthreads();
  if (tid == 0) out[nidx] = red[0] + red[1] + red[2] + red[3] + spb[nidx];
}

extern "C" void kernel_launch(void* const* d_in, const int* in_sizes, int n_in,
                              void* d_out, int out_size, void* d_ws, size_t ws_size,
                              hipStream_t stream) {
  const float* x        = (const float*)d_in[0];
  const float* Wi       = (const float*)d_in[1];
  const float* bi       = (const float*)d_in[2];
  const float* ln_g     = (const float*)d_in[3];
  const float* ln_b     = (const float*)d_in[4];
  const float* in_w     = (const float*)d_in[5];
  const float* conv_w   = (const float*)d_in[6];
  const float* conv_b   = (const float*)d_in[7];
  const float* xproj_w  = (const float*)d_in[8];
  const float* dtproj_w = (const float*)d_in[9];
  const float* dtproj_b = (const float*)d_in[10];
  const float* A_log    = (const float*)d_in[11];
  const float* Dp       = (const float*)d_in[12];
  const float* out_w    = (const float*)d_in[13];
  const float* fn_g     = (const float*)d_in[14];
  const float* fn_b     = (const float*)d_in[15];
  const float* sp_w     = (const float*)d_in[16];
  const float* sp_b     = (const float*)d_in[17];
  float* out  = (float*)d_out;
  float* ws_f = (float*)d_ws;

  float* h_buf  = ws_f;                // 1048576
  float* xz     = ws_f + 1048576;      // 4194304
  float* u_buf  = ws_f + 5242880;      // 2097152
  float* xdbl   = ws_f + 7340032;      // 131072
  float* delta  = ws_f + 7471104;      // 2097152 (also xproj partials)
  float* hend   = ws_f + 9568256;      // 524288
  float* pend   = ws_f + 10092544;     // 524288
  __bf16* nbf   = (__bf16*)(ws_f + 10617856);  // 1M bf16
  __bf16* ybf   = (__bf16*)(ws_f + 11142144);  // 2M bf16
  __bf16* wbf   = (__bf16*)(ws_f + 12190720);  // 8M bf16 (in_w)
  __bf16* xdblbf= (__bf16*)(ws_f + 16385024);  // 128K bf16
  __bf16* dtwbf = (__bf16*)(ws_f + 16450560);  // 128K bf16
  __bf16* ubf   = (__bf16*)(ws_f + 16516096);  // 2M bf16
  __bf16* xpbf  = (__bf16*)(ws_f + 17564672);  // 256K bf16
  __bf16* owbf  = (__bf16*)(ws_f + 17695744);  // 2M bf16 (out_w)
  float* skmf   = u_buf;               // MFMA split-K partials overlay (Wi/out)
  float* skxp   = delta;               // xproj split-K partials overlay
  float* cmpart = hend;                // colmean partials overlay

  const dim3 blk(256);

  // prologue: convert x + Wi in one launch; Wi GEMM split-K=4
  f2bf4_k<<<1024, blk, 0, stream>>>(x, nbf, L_*D_, Wi, wbf, D_*D_,
                                    x, nbf, 0, x, nbf, 0);
  gemm_mfma_sk<<<dim3(D_/128, L_/128, ZSPL), blk, 0, stream>>>(
      nbf, wbf, skmf, L_, D_, D_, D_/ZSPL);
  mfma_sk_reduce<<<dim3(L_*D_/4/256), blk, 0, stream>>>(
      skmf, bi, h_buf, nullptr, L_*D_, D_, ZSPL, 4);

  for (int i = 0; i < NB_; ++i) {
    f2bf4_k<<<3264, blk, 0, stream>>>(
        in_w    + (size_t)i*2*ED_*D_, wbf,   2*ED_*D_,
        xproj_w + (size_t)i*128*ED_,  xpbf,  128*ED_,
        dtproj_w+ (size_t)i*ED_*DTR_, dtwbf, ED_*DTR_,
        out_w   + (size_t)i*D_*ED_,   owbf,  D_*ED_);
    layernorm_bf_k<<<L_, blk, 0, stream>>>(h_buf, ln_g + i*D_, ln_b + i*D_, nbf);
    // xz = normed @ in_w^T
    gemm_mfma<<<dim3(2*ED_/128, L_/128), blk, 0, stream>>>(
        nbf, D_, wbf, D_, nullptr, xz, 2*ED_, D_, 0);
    conv_silu_k<<<dim3(ED_/256, L_/8), blk, 0, stream>>>(
        xz, conv_w + (size_t)i*ED_*KCONV, conv_b + (size_t)i*ED_, u_buf, ubf);
    // x_dbl = u @ xproj^T  (bf16 MFMA split-K=16)
    gemm_mfma_sk<<<dim3(1, L_/128, XPZ), blk, 0, stream>>>(
        ubf, xpbf, skxp, L_, 128, ED_, ED_/XPZ);
    mfma_sk_reduce<<<dim3(L_*128/4/256), blk, 0, stream>>>(
        skxp, nullptr, xdbl, xdblbf, L_*128, 128, XPZ, 8);
    // delta = softplus(dt @ dtproj^T + b)  (bf16 MFMA, K=64)
    gemm_mfma<<<dim3(ED_/128, L_/128), blk, 0, stream>>>(
        xdblbf, 128, dtwbf, DTR_, dtproj_b + (size_t)i*ED_, delta, ED_, DTR_, 2 | 4);
    // chunked scan
    scan_phase1<<<dim3(ED_/8, NCH), blk, 0, stream>>>(
        delta, u_buf, xdbl, A_log + (size_t)i*ED_*NST, hend, pend);
    scan_phase3<<<dim3(ED_/8, NCH), blk, 0, stream>>>(
        delta, u_buf, xdbl, A_log + (size_t)i*ED_*NST, hend, pend,
        Dp + (size_t)i*ED_, xz, ybf);
    // h += y @ out_w^T   (bf16 MFMA, split-K=4)
    gemm_mfma_sk<<<dim3(D_/128, L_/128, ZSPL), blk, 0, stream>>>(
        ybf, owbf, skmf, L_, D_, ED_, ED_/ZSPL);
    mfma_sk_reduce<<<dim3(L_*D_/4/256), blk, 0, stream>>>(
        skmf, nullptr, h_buf, nullptr, L_*D_, D_, ZSPL, 1);
  }

  layernorm_k<<<L_, blk, 0, stream>>>(h_buf, fn_g, fn_b, out);
  colmean_part_k<<<dim3(D_/256, 32), blk, 0, stream>>>(out, cmpart);
  state_fused_k<<<NST, blk, 0, stream>>>(cmpart, sp_w, sp_b, out + (size_t)L_*D_);
}

// Round 17
// 651.034 us; speedup vs baseline: 1.0621x; 1.0128x over previous
//
#include <hip/hip_runtime.h>
#include <math.h>

#define D_    1024
#define ED_   2048
#define NST   32
#define KCONV 4
#define DTR_  64
#define L_    1024
#define NB_   4
#define NCH   8
#define CHUNK (L_ / NCH)
#define ZSPL  4
#define XPZ   16

typedef __bf16 bf16_8 __attribute__((ext_vector_type(8)));
typedef __bf16 bf16_4 __attribute__((ext_vector_type(4)));
typedef float  f32x4  __attribute__((ext_vector_type(4)));

__device__ __forceinline__ float softplus_f(float x) {
  return x > 20.f ? x : log1pf(expf(x));
}
__device__ __forceinline__ float silu_f(float x) {
  return x / (1.f + expf(-x));
}

// XCD-aware bijective remap (nwg % 8 == 0 for all our GEMM grids)
__device__ __forceinline__ int xcd_swz(int lin, int nwg) {
  const int q = nwg >> 3;
  return (lin & 7) * q + (lin >> 3);
}

// segmented fp32 -> bf16 (each count multiple of 8)
__global__ __launch_bounds__(256) void f2bf4_k(
    const float* __restrict__ i0, __bf16* __restrict__ o0, int n0,
    const float* __restrict__ i1, __bf16* __restrict__ o1, int n1,
    const float* __restrict__ i2, __bf16* __restrict__ o2, int n2,
    const float* __restrict__ i3, __bf16* __restrict__ o3, int n3)
{
  int gid = blockIdx.x * 256 + threadIdx.x;
  const int u0 = n0 >> 3, u1 = n1 >> 3, u2 = n2 >> 3, u3 = n3 >> 3;
  const float* in; __bf16* out;
  if (gid < u0) { in = i0; out = o0; }
  else if ((gid -= u0) < u1) { in = i1; out = o1; }
  else if ((gid -= u1) < u2) { in = i2; out = o2; }
  else if ((gid -= u2) < u3) { in = i3; out = o3; }
  else return;
  const int i = gid * 8;
  const float4 a = *reinterpret_cast<const float4*>(in + i);
  const float4 b = *reinterpret_cast<const float4*>(in + i + 4);
  bf16_8 v;
  v[0]=(__bf16)a.x; v[1]=(__bf16)a.y; v[2]=(__bf16)a.z; v[3]=(__bf16)a.w;
  v[4]=(__bf16)b.x; v[5]=(__bf16)b.y; v[6]=(__bf16)b.z; v[7]=(__bf16)b.w;
  *reinterpret_cast<bf16_8*>(out + i) = v;
}

// ---- MFMA bf16 GEMM (128x128, BK=64, XOR-swizzled LDS, XCD-swizzled grid) ----
// flags: 1=accumulate, 2=softplus, 4=bias
__global__ __launch_bounds__(256) void gemm_mfma(
    const __bf16* __restrict__ A, int lda,
    const __bf16* __restrict__ W, int ldw,
    const float* __restrict__ bias, float* __restrict__ C, int ldc,
    int K, int flags)
{
  __shared__ __bf16 As[128 * 64];
  __shared__ __bf16 Ws[128 * 64];
  const int tid  = threadIdx.x;
  const int lane = tid & 63;
  const int w    = tid >> 6;
  const int wr   = w >> 1, wc = w & 1;
  const int nwg  = gridDim.x * gridDim.y;
  const int swz  = xcd_swz(blockIdx.y * gridDim.x + blockIdx.x, nwg);
  const int bx   = swz % gridDim.x, by = swz / gridDim.x;
  const int row0 = by * 128, col0 = bx * 128;

  f32x4 acc[4][4] = {};

  for (int k0 = 0; k0 < K; k0 += 64) {
    #pragma unroll
    for (int j = 0; j < 4; ++j) {
      const int inst = w * 4 + j;
      const int row  = inst * 8 + (lane >> 3);
      const int lu   = (lane & 7) ^ (row & 7);
      __builtin_amdgcn_global_load_lds(
          (const __attribute__((address_space(1))) void*)(A + (size_t)(row0 + row) * lda + k0 + lu * 8),
          (__attribute__((address_space(3))) void*)(&As[inst * 512]), 16, 0, 0);
      __builtin_amdgcn_global_load_lds(
          (const __attribute__((address_space(1))) void*)(W + (size_t)(col0 + row) * ldw + k0 + lu * 8),
          (__attribute__((address_space(3))) void*)(&Ws[inst * 512]), 16, 0, 0);
    }
    __syncthreads();
    const int r16 = lane & 15;
    const int uq  = lane >> 4;
    #pragma unroll
    for (int ks = 0; ks < 2; ++ks) {
      bf16_8 af[4], bfr[4];
      #pragma unroll
      for (int m = 0; m < 4; ++m) {
        const int row = wr * 64 + m * 16 + r16;
        const int pu  = (ks * 4 + uq) ^ (row & 7);
        af[m] = *reinterpret_cast<const bf16_8*>(&As[row * 64 + pu * 8]);
      }
      #pragma unroll
      for (int n = 0; n < 4; ++n) {
        const int row = wc * 64 + n * 16 + r16;
        const int pu  = (ks * 4 + uq) ^ (row & 7);
        bfr[n] = *reinterpret_cast<const bf16_8*>(&Ws[row * 64 + pu * 8]);
      }
      #pragma unroll
      for (int m = 0; m < 4; ++m)
        #pragma unroll
        for (int n = 0; n < 4; ++n)
          acc[m][n] = __builtin_amdgcn_mfma_f32_16x16x32_bf16(af[m], bfr[n], acc[m][n], 0, 0, 0);
    }
    __syncthreads();
  }

  const int crow = (lane >> 4) * 4;
  const int ccol = lane & 15;
  #pragma unroll
  for (int m = 0; m < 4; ++m)
    #pragma unroll
    for (int n = 0; n < 4; ++n) {
      const int col = col0 + wc * 64 + n * 16 + ccol;
      const float bv = (flags & 4) ? bias[col] : 0.f;
      #pragma unroll
      for (int r = 0; r < 4; ++r) {
        const int row = row0 + wr * 64 + m * 16 + crow + r;
        float* cp = C + (size_t)row * ldc + col;
        float v = acc[m][n][r] + bv;
        if (flags & 2) v = softplus_f(v);
        if (flags & 1) v += *cp;
        *cp = v;
      }
    }
}

// split-K MFMA GEMM (lda=ldw=K)
__global__ __launch_bounds__(256) void gemm_mfma_sk(
    const __bf16* __restrict__ A, const __bf16* __restrict__ W,
    float* __restrict__ partials, int M, int N, int K, int Kc)
{
  __shared__ __bf16 As[128 * 64];
  __shared__ __bf16 Ws[128 * 64];
  const int tid  = threadIdx.x;
  const int lane = tid & 63;
  const int w    = tid >> 6;
  const int wr   = w >> 1, wc = w & 1;
  const int nwg  = gridDim.x * gridDim.y * gridDim.z;
  const int lin  = (blockIdx.z * gridDim.y + blockIdx.y) * gridDim.x + blockIdx.x;
  const int swz  = xcd_swz(lin, nwg);
  const int bx   = swz % gridDim.x;
  const int tmp  = swz / gridDim.x;
  const int by   = tmp % gridDim.y, bz = tmp / gridDim.y;
  const int row0 = by * 128, col0 = bx * 128;
  const int kbase = bz * Kc;

  f32x4 acc[4][4] = {};

  for (int k0 = kbase; k0 < kbase + Kc; k0 += 64) {
    #pragma unroll
    for (int j = 0; j < 4; ++j) {
      const int inst = w * 4 + j;
      const int row  = inst * 8 + (lane >> 3);
      const int lu   = (lane & 7) ^ (row & 7);
      __builtin_amdgcn_global_load_lds(
          (const __attribute__((address_space(1))) void*)(A + (size_t)(row0 + row) * K + k0 + lu * 8),
          (__attribute__((address_space(3))) void*)(&As[inst * 512]), 16, 0, 0);
      __builtin_amdgcn_global_load_lds(
          (const __attribute__((address_space(1))) void*)(W + (size_t)(col0 + row) * K + k0 + lu * 8),
          (__attribute__((address_space(3))) void*)(&Ws[inst * 512]), 16, 0, 0);
    }
    __syncthreads();
    const int r16 = lane & 15;
    const int uq  = lane >> 4;
    #pragma unroll
    for (int ks = 0; ks < 2; ++ks) {
      bf16_8 af[4], bfr[4];
      #pragma unroll
      for (int m = 0; m < 4; ++m) {
        const int row = wr * 64 + m * 16 + r16;
        const int pu  = (ks * 4 + uq) ^ (row & 7);
        af[m] = *reinterpret_cast<const bf16_8*>(&As[row * 64 + pu * 8]);
      }
      #pragma unroll
      for (int n = 0; n < 4; ++n) {
        const int row = wc * 64 + n * 16 + r16;
        const int pu  = (ks * 4 + uq) ^ (row & 7);
        bfr[n] = *reinterpret_cast<const bf16_8*>(&Ws[row * 64 + pu * 8]);
      }
      #pragma unroll
      for (int m = 0; m < 4; ++m)
        #pragma unroll
        for (int n = 0; n < 4; ++n)
          acc[m][n] = __builtin_amdgcn_mfma_f32_16x16x32_bf16(af[m], bfr[n], acc[m][n], 0, 0, 0);
    }
    __syncthreads();
  }

  float* base = partials + (size_t)bz * M * N;
  const int crow = (lane >> 4) * 4;
  const int ccol = lane & 15;
  #pragma unroll
  for (int m = 0; m < 4; ++m)
    #pragma unroll
    for (int n = 0; n < 4; ++n) {
      const int col = col0 + wc * 64 + n * 16 + ccol;
      #pragma unroll
      for (int r = 0; r < 4; ++r) {
        const int row = row0 + wr * 64 + m * 16 + crow + r;
        base[(size_t)row * N + col] = acc[m][n][r];
      }
    }
}

// generic reduce (xproj + final out-reduce)
__global__ __launch_bounds__(256) void mfma_sk_reduce(
    const float* __restrict__ partials, const float* __restrict__ bias,
    float* __restrict__ C, __bf16* __restrict__ Cbf,
    int elems, int ncols, int nz, int flags)
{
  const int i = (blockIdx.x * 256 + threadIdx.x) * 4;
  if (i >= elems) return;
  float4 s = *reinterpret_cast<const float4*>(partials + i);
  for (int z = 1; z < nz; ++z) {
    const float4 p = *reinterpret_cast<const float4*>(partials + (size_t)z * elems + i);
    s.x += p.x; s.y += p.y; s.z += p.z; s.w += p.w;
  }
  if (flags & 4) {
    const float4 bv = *reinterpret_cast<const float4*>(bias + (i % ncols));
    s.x += bv.x; s.y += bv.y; s.z += bv.z; s.w += bv.w;
  }
  if (flags & 1) {
    const float4 ov = *reinterpret_cast<const float4*>(C + i);
    s.x += ov.x; s.y += ov.y; s.z += ov.z; s.w += ov.w;
  }
  *reinterpret_cast<float4*>(C + i) = s;
  if (flags & 8) {
    bf16_4 b;
    b[0]=(__bf16)s.x; b[1]=(__bf16)s.y; b[2]=(__bf16)s.z; b[3]=(__bf16)s.w;
    *reinterpret_cast<bf16_4*>(Cbf + i) = b;
  }
}

// fused: reduce ZSPL split-K partials (+bias or +acc) -> h_buf, then LN -> bf16
// one block per row. flags: 1=acc into h, 4=bias
__global__ __launch_bounds__(256) void reduce_ln_k(
    const float* __restrict__ partials, const float* __restrict__ bias,
    float* __restrict__ hbuf, const float* __restrict__ g,
    const float* __restrict__ b, __bf16* __restrict__ outbf, int flags)
{
  __shared__ float red[8];
  const int row = blockIdx.x;
  const int tid = threadIdx.x;
  const int c = tid * 4;
  const size_t off = (size_t)row * D_ + c;
  float4 v = *reinterpret_cast<const float4*>(partials + off);
  #pragma unroll
  for (int z = 1; z < ZSPL; ++z) {
    const float4 p = *reinterpret_cast<const float4*>(partials + (size_t)z * (L_*D_) + off);
    v.x += p.x; v.y += p.y; v.z += p.z; v.w += p.w;
  }
  if (flags & 4) {
    const float4 bv = *reinterpret_cast<const float4*>(bias + c);
    v.x += bv.x; v.y += bv.y; v.z += bv.z; v.w += bv.w;
  }
  if (flags & 1) {
    const float4 ov = *reinterpret_cast<const float4*>(hbuf + off);
    v.x += ov.x; v.y += ov.y; v.z += ov.z; v.w += ov.w;
  }
  *reinterpret_cast<float4*>(hbuf + off) = v;

  float s = v.x + v.y + v.z + v.w;
  #pragma unroll
  for (int o = 32; o; o >>= 1) s += __shfl_down(s, o, 64);
  if ((tid & 63) == 0) red[tid >> 6] = s;
  __syncthreads();
  const float m = (red[0] + red[1] + red[2] + red[3]) * (1.f / D_);
  float dx0 = v.x - m, dx1 = v.y - m, dx2 = v.z - m, dx3 = v.w - m;
  float ss = dx0*dx0 + dx1*dx1 + dx2*dx2 + dx3*dx3;
  #pragma unroll
  for (int o = 32; o; o >>= 1) ss += __shfl_down(ss, o, 64);
  if ((tid & 63) == 0) red[4 + (tid >> 6)] = ss;
  __syncthreads();
  const float var = (red[4] + red[5] + red[6] + red[7]) * (1.f / D_);
  const float rs = rsqrtf(var + 1e-5f);
  const float4 gv = *reinterpret_cast<const float4*>(g + c);
  const float4 bv = *reinterpret_cast<const float4*>(b + c);
  bf16_4 o;
  o[0] = (__bf16)(dx0 * rs * gv.x + bv.x);
  o[1] = (__bf16)(dx1 * rs * gv.y + bv.y);
  o[2] = (__bf16)(dx2 * rs * gv.z + bv.z);
  o[3] = (__bf16)(dx3 * rs * gv.w + bv.w);
  *reinterpret_cast<bf16_4*>(outbf + off) = o;
}

// layernorm, fp32 out (final LN)
__global__ __launch_bounds__(256) void layernorm_k(
    const float* __restrict__ x, const float* __restrict__ g,
    const float* __restrict__ b, float* __restrict__ out)
{
  __shared__ float red[8];
  const int row = blockIdx.x;
  const int tid = threadIdx.x;
  const float* xr = x + (size_t)row * D_;
  float4 v = *reinterpret_cast<const float4*>(xr + tid * 4);
  float s = v.x + v.y + v.z + v.w;
  #pragma unroll
  for (int off = 32; off; off >>= 1) s += __shfl_down(s, off, 64);
  if ((tid & 63) == 0) red[tid >> 6] = s;
  __syncthreads();
  const float m = (red[0] + red[1] + red[2] + red[3]) * (1.f / D_);
  float dx0 = v.x - m, dx1 = v.y - m, dx2 = v.z - m, dx3 = v.w - m;
  float ss = dx0*dx0 + dx1*dx1 + dx2*dx2 + dx3*dx3;
  #pragma unroll
  for (int off = 32; off; off >>= 1) ss += __shfl_down(ss, off, 64);
  if ((tid & 63) == 0) red[4 + (tid >> 6)] = ss;
  __syncthreads();
  const float var = (red[4] + red[5] + red[6] + red[7]) * (1.f / D_);
  const float rs = rsqrtf(var + 1e-5f);
  const int c = tid * 4;
  const float4 gv = *reinterpret_cast<const float4*>(g + c);
  const float4 bv = *reinterpret_cast<const float4*>(b + c);
  float4 o;
  o.x = dx0 * rs * gv.x + bv.x;
  o.y = dx1 * rs * gv.y + bv.y;
  o.z = dx2 * rs * gv.z + bv.z;
  o.w = dx3 * rs * gv.w + bv.w;
  *reinterpret_cast<float4*>(out + (size_t)row * D_ + c) = o;
}

// depthwise causal conv K=4 + bias + silu; 8 timesteps/thread; fp32 + bf16 out
__global__ __launch_bounds__(256) void conv_silu_k(
    const float* __restrict__ xz, const float* __restrict__ cw,
    const float* __restrict__ cb, float* __restrict__ u, __bf16* __restrict__ ub)
{
  const int e = blockIdx.x * 256 + threadIdx.x;
  const int t0 = blockIdx.y * 8;
  const float w0 = cw[e*4+0], w1 = cw[e*4+1], w2 = cw[e*4+2], w3 = cw[e*4+3];
  const float b = cb[e];
  float x0 = (t0 >= 3) ? xz[(size_t)(t0-3)*(2*ED_)+e] : 0.f;
  float x1 = (t0 >= 2) ? xz[(size_t)(t0-2)*(2*ED_)+e] : 0.f;
  float x2 = (t0 >= 1) ? xz[(size_t)(t0-1)*(2*ED_)+e] : 0.f;
  #pragma unroll
  for (int j = 0; j < 8; ++j) {
    const float x3 = xz[(size_t)(t0+j)*(2*ED_)+e];
    const float uv = silu_f(b + w0*x0 + w1*x1 + w2*x2 + w3*x3);
    u[(size_t)(t0+j)*ED_+e] = uv;
    ub[(size_t)(t0+j)*ED_+e] = (__bf16)uv;
    x0 = x1; x1 = x2; x2 = x3;
  }
}

// ---- chunked selective scan ----
// phase 1: 32-step tiles (half the barriers), chain unrolled x2.
__global__ __launch_bounds__(256) void scan_phase1(
    const float* __restrict__ delta, const float* __restrict__ u,
    const float* __restrict__ xdbl, const float* __restrict__ A_log,
    float* __restrict__ hend, float* __restrict__ Pend)
{
  __shared__ float dl[32][8], ul[32][8];
  __shared__ float bl[32][32];
  const int tid = threadIdx.x;
  const int n = tid & 31;
  const int c = tid >> 5;
  const int e0 = blockIdx.x * 8;
  const int e = e0 + c;
  const int ch = blockIdx.y;
  const float a = -expf(A_log[e * NST + n]);
  float h = 0.f, S = 0.f;
  const int t0 = ch * CHUNK;
  const int s_t = tid >> 3, s_e = tid & 7;       // 32 x 8
  const int b_t = tid >> 3, b_c = (tid & 7) * 4; // 32 x 8 float4 = 32x32

  float rg_d, rg_u;
  float4 rg_b;
  rg_d = delta[(size_t)(t0 + s_t) * ED_ + e0 + s_e];
  rg_u = u[(size_t)(t0 + s_t) * ED_ + e0 + s_e];
  rg_b = *reinterpret_cast<const float4*>(&xdbl[(size_t)(t0 + b_t) * 128 + 64 + b_c]);

  for (int tb = 0; tb < CHUNK; tb += 32) {
    dl[s_t][s_e] = rg_d;
    ul[s_t][s_e] = rg_u;
    *reinterpret_cast<float4*>(&bl[b_t][b_c]) = rg_b;
    __syncthreads();
    if (tb + 32 < CHUNK) {
      const int t = t0 + tb + 32 + s_t;
      rg_d = delta[(size_t)t * ED_ + e0 + s_e];
      rg_u = u[(size_t)t * ED_ + e0 + s_e];
      rg_b = *reinterpret_cast<const float4*>(&xdbl[(size_t)(t0 + tb + 32 + b_t) * 128 + 64 + b_c]);
    }
    #pragma unroll
    for (int jp = 0; jp < 16; ++jp) {
      const float sd1 = dl[2*jp][c],   uv1 = ul[2*jp][c],   B1 = bl[2*jp][n];
      const float sd2 = dl[2*jp+1][c], uv2 = ul[2*jp+1][c], B2 = bl[2*jp+1][n];
      const float dA1 = __expf(sd1 * a);
      const float dA2 = __expf(sd2 * a);
      const float b1 = sd1 * uv1 * B1;
      const float b2 = sd2 * uv2 * B2;
      h = fmaf(dA1 * dA2, h, fmaf(dA2, b1, b2));
      S += sd1 + sd2;
    }
    __syncthreads();
  }
  const int idx = ch * (ED_ * NST) + blockIdx.x * 256 + tid;
  hend[idx] = h;
  Pend[idx] = __expf(a * S);
}

// phase 3 (round-11 proven config): inline h_in combine + pipelined LDS tiles
__global__ __launch_bounds__(256, 7) void scan_phase3(
    const float* __restrict__ delta, const float* __restrict__ u,
    const float* __restrict__ xdbl, const float* __restrict__ A_log,
    const float* __restrict__ hend, const float* __restrict__ Pend,
    const float* __restrict__ Dp,
    const float* __restrict__ xz, __bf16* __restrict__ y)
{
  __shared__ float p_lds[8][16][33];
  __shared__ float dl[16][8], ul[16][8], zl[16][8];
  __shared__ float bc[16][64];
  const int tid = threadIdx.x;
  const int n = tid & 31;
  const int c = tid >> 5;
  const int e0 = blockIdx.x * 8;
  const int e = e0 + c;
  const int ch = blockIdx.y;
  const float a = -expf(A_log[e * NST + n]);
  const float dp = Dp[e];

  float h = 0.f;
  {
    const int sidx = blockIdx.x * 256 + tid;
    for (int cc = 0; cc < ch; ++cc) {
      const int off = cc * (ED_ * NST) + sidx;
      h = fmaf(Pend[off], h, hend[off]);
    }
  }

  const int t0 = ch * CHUNK;
  const int r = n & 15, half = n >> 4;
  const int s_t  = (tid & 127) >> 3;
  const int s_e  = tid & 7;
  const int b_t  = tid >> 4;
  const int b_c  = (tid & 15) * 4;

  float rg_a = 0.f, rg_z = 0.f;
  float4 rg_bc;
  {
    const int t = t0 + s_t;
    if (tid < 128) {
      rg_a = delta[(size_t)t * ED_ + e0 + s_e];
      rg_z = xz[(size_t)t * (2*ED_) + ED_ + e0 + s_e];
    } else {
      rg_a = u[(size_t)t * ED_ + e0 + s_e];
    }
    rg_bc = *reinterpret_cast<const float4*>(&xdbl[(size_t)(t0 + b_t) * 128 + 64 + b_c]);
  }

  for (int tb = 0; tb < CHUNK; tb += 16) {
    if (tid < 128) { dl[s_t][s_e] = rg_a; zl[s_t][s_e] = rg_z; }
    else          { ul[s_t][s_e] = rg_a; }
    *reinterpret_cast<float4*>(&bc[b_t][b_c]) = rg_bc;
    __syncthreads();
    if (tb + 16 < CHUNK) {
      const int t = t0 + tb + 16 + s_t;
      if (tid < 128) {
        rg_a = delta[(size_t)t * ED_ + e0 + s_e];
        rg_z = xz[(size_t)t * (2*ED_) + ED_ + e0 + s_e];
      } else {
        rg_a = u[(size_t)t * ED_ + e0 + s_e];
      }
      rg_bc = *reinterpret_cast<const float4*>(&xdbl[(size_t)(t0 + tb + 16 + b_t) * 128 + 64 + b_c]);
    }
    #pragma unroll
    for (int j = 0; j < 16; ++j) {
      const float sd = dl[j][c];
      const float uv = ul[j][c];
      const float Bv = bc[j][n];
      const float Cv = bc[j][32 + n];
      const float dA = __expf(sd * a);
      h = fmaf(dA, h, sd * uv * Bv);
      p_lds[c][j][n] = h * Cv;
    }
    __syncthreads();
    float s = 0.f;
    #pragma unroll
    for (int k = 0; k < 16; ++k) s += p_lds[c][r][half * 16 + k];
    s += __shfl_xor(s, 16, 64);
    if (half == 0) {
      const float uvt = ul[r][c];
      const float zv  = zl[r][c];
      y[(size_t)(t0 + tb + r) * ED_ + e] = (__bf16)((s + uvt * dp) * silu_f(zv));
    }
    __syncthreads();
  }
}

// column-mean partials (coalesced)
__global__ __launch_bounds__(256) void colmean_part_k(
    const float* __restrict__ hf, float* __restrict__ part)
{
  const int d = blockIdx.x * 256 + threadIdx.x;
  const int tc = blockIdx.y;
  float s = 0.f;
  #pragma unroll 8
  for (int j = 0; j < 32; ++j) s += hf[(size_t)(tc * 32 + j) * D_ + d];
  part[tc * D_ + d] = s;
}

// fused finalize + state projection
__global__ __launch_bounds__(256) void state_fused_k(
    const float* __restrict__ part, const float* __restrict__ spw,
    const float* __restrict__ spb, float* __restrict__ out)
{
  __shared__ float red[4];
  const int nidx = blockIdx.x;
  const int tid = threadIdx.x;
  float s = 0.f;
  for (int d = tid; d < D_; d += 256) {
    float cm = 0.f;
    #pragma unroll
    for (int c = 0; c < 32; ++c) cm += part[c * D_ + d];
    s += cm * (1.f / L_) * spw[(size_t)nidx * D_ + d];
  }
  #pragma unroll
  for (int off = 32; off; off >>= 1) s += __shfl_down(s, off, 64);
  if ((tid & 63) == 0) red[tid >> 6] = s;
  __syncthreads();
  if (tid == 0) out[nidx] = red[0] + red[1] + red[2] + red[3] + spb[nidx];
}

extern "C" void kernel_launch(void* const* d_in, const int* in_sizes, int n_in,
                              void* d_out, int out_size, void* d_ws, size_t ws_size,
                              hipStream_t stream) {
  const float* x        = (const float*)d_in[0];
  const float* Wi       = (const float*)d_in[1];
  const float* bi       = (const float*)d_in[2];
  const float* ln_g     = (const float*)d_in[3];
  const float* ln_b     = (const float*)d_in[4];
  const float* in_w     = (const float*)d_in[5];
  const float* conv_w   = (const float*)d_in[6];
  const float* conv_b   = (const float*)d_in[7];
  const float* xproj_w  = (const float*)d_in[8];
  const float* dtproj_w = (const float*)d_in[9];
  const float* dtproj_b = (const float*)d_in[10];
  const float* A_log    = (const float*)d_in[11];
  const float* Dp       = (const float*)d_in[12];
  const float* out_w    = (const float*)d_in[13];
  const float* fn_g     = (const float*)d_in[14];
  const float* fn_b     = (const float*)d_in[15];
  const float* sp_w     = (const float*)d_in[16];
  const float* sp_b     = (const float*)d_in[17];
  float* out  = (float*)d_out;
  float* ws_f = (float*)d_ws;

  float* h_buf  = ws_f;                // 1048576
  float* xz     = ws_f + 1048576;      // 4194304
  float* u_buf  = ws_f + 5242880;      // 2097152
  float* xdbl   = ws_f + 7340032;      // 131072
  float* delta  = ws_f + 7471104;      // 2097152 (also xproj partials)
  float* hend   = ws_f + 9568256;      // 524288
  float* pend   = ws_f + 10092544;     // 524288
  __bf16* nbf   = (__bf16*)(ws_f + 10617856);  // 1M bf16
  __bf16* ybf   = (__bf16*)(ws_f + 11142144);  // 2M bf16
  __bf16* wbf   = (__bf16*)(ws_f + 12190720);  // 8M bf16 (in_w)
  __bf16* xdblbf= (__bf16*)(ws_f + 16385024);  // 128K bf16
  __bf16* dtwbf = (__bf16*)(ws_f + 16450560);  // 128K bf16
  __bf16* ubf   = (__bf16*)(ws_f + 16516096);  // 2M bf16
  __bf16* xpbf  = (__bf16*)(ws_f + 17564672);  // 256K bf16
  __bf16* owbf  = (__bf16*)(ws_f + 17695744);  // 2M bf16 (out_w)
  float* skmf   = u_buf;               // MFMA split-K partials overlay (Wi/out)
  float* skxp   = delta;               // xproj split-K partials overlay
  float* cmpart = hend;                // colmean partials overlay

  const dim3 blk(256);

  // prologue: convert x + Wi; Wi GEMM split-K=4; fused reduce + LN(block 0)
  f2bf4_k<<<1024, blk, 0, stream>>>(x, nbf, L_*D_, Wi, wbf, D_*D_,
                                    x, nbf, 0, x, nbf, 0);
  gemm_mfma_sk<<<dim3(D_/128, L_/128, ZSPL), blk, 0, stream>>>(
      nbf, wbf, skmf, L_, D_, D_, D_/ZSPL);
  reduce_ln_k<<<L_, blk, 0, stream>>>(
      skmf, bi, h_buf, ln_g, ln_b, nbf, 4);

  for (int i = 0; i < NB_; ++i) {
    f2bf4_k<<<3264, blk, 0, stream>>>(
        in_w    + (size_t)i*2*ED_*D_, wbf,   2*ED_*D_,
        xproj_w + (size_t)i*128*ED_,  xpbf,  128*ED_,
        dtproj_w+ (size_t)i*ED_*DTR_, dtwbf, ED_*DTR_,
        out_w   + (size_t)i*D_*ED_,   owbf,  D_*ED_);
    // xz = normed @ in_w^T  (nbf prepared by previous reduce_ln)
    gemm_mfma<<<dim3(2*ED_/128, L_/128), blk, 0, stream>>>(
        nbf, D_, wbf, D_, nullptr, xz, 2*ED_, D_, 0);
    conv_silu_k<<<dim3(ED_/256, L_/8), blk, 0, stream>>>(
        xz, conv_w + (size_t)i*ED_*KCONV, conv_b + (size_t)i*ED_, u_buf, ubf);
    // x_dbl = u @ xproj^T  (bf16 MFMA split-K=16)
    gemm_mfma_sk<<<dim3(1, L_/128, XPZ), blk, 0, stream>>>(
        ubf, xpbf, skxp, L_, 128, ED_, ED_/XPZ);
    mfma_sk_reduce<<<dim3(L_*128/4/256), blk, 0, stream>>>(
        skxp, nullptr, xdbl, xdblbf, L_*128, 128, XPZ, 8);
    // delta = softplus(dt @ dtproj^T + b)  (bf16 MFMA, K=64)
    gemm_mfma<<<dim3(ED_/128, L_/128), blk, 0, stream>>>(
        xdblbf, 128, dtwbf, DTR_, dtproj_b + (size_t)i*ED_, delta, ED_, DTR_, 2 | 4);
    // chunked scan
    scan_phase1<<<dim3(ED_/8, NCH), blk, 0, stream>>>(
        delta, u_buf, xdbl, A_log + (size_t)i*ED_*NST, hend, pend);
    scan_phase3<<<dim3(ED_/8, NCH), blk, 0, stream>>>(
        delta, u_buf, xdbl, A_log + (size_t)i*ED_*NST, hend, pend,
        Dp + (size_t)i*ED_, xz, ybf);
    // h += y @ out_w^T (split-K=4); fused reduce(+acc)+LN for next block
    gemm_mfma_sk<<<dim3(D_/128, L_/128, ZSPL), blk, 0, stream>>>(
        ybf, owbf, skmf, L_, D_, ED_, ED_/ZSPL);
    if (i < NB_ - 1) {
      reduce_ln_k<<<L_, blk, 0, stream>>>(
          skmf, nullptr, h_buf, ln_g + (i+1)*D_, ln_b + (i+1)*D_, nbf, 1);
    } else {
      mfma_sk_reduce<<<dim3(L_*D_/4/256), blk, 0, stream>>>(
          skmf, nullptr, h_buf, nullptr, L_*D_, D_, ZSPL, 1);
    }
  }

  layernorm_k<<<L_, blk, 0, stream>>>(h_buf, fn_g, fn_b, out);
  colmean_part_k<<<dim3(D_/256, 32), blk, 0, stream>>>(out, cmpart);
  state_fused_k<<<NST, blk, 0, stream>>>(cmpart, sp_w, sp_b, out + (size_t)L_*D_);
}

// Round 18
// 643.664 us; speedup vs baseline: 1.0743x; 1.0115x over previous
//
#include <hip/hip_runtime.h>
#include <math.h>

#define D_    1024
#define ED_   2048
#define NST   32
#define KCONV 4
#define DTR_  64
#define L_    1024
#define NB_   4
#define NCH   8
#define CHUNK (L_ / NCH)
#define ZSPL  4
#define XPZ   16

typedef __bf16 bf16_8 __attribute__((ext_vector_type(8)));
typedef __bf16 bf16_4 __attribute__((ext_vector_type(4)));
typedef float  f32x4  __attribute__((ext_vector_type(4)));

__device__ __forceinline__ float softplus_f(float x) {
  return x > 20.f ? x : log1pf(expf(x));
}
__device__ __forceinline__ float silu_f(float x) {
  return x / (1.f + expf(-x));
}

// XCD-aware bijective remap (nwg % 8 == 0 for all our GEMM grids)
__device__ __forceinline__ int xcd_swz(int lin, int nwg) {
  const int q = nwg >> 3;
  return (lin & 7) * q + (lin >> 3);
}

// segmented fp32 -> bf16 (each count multiple of 8)
__global__ __launch_bounds__(256) void f2bf4_k(
    const float* __restrict__ i0, __bf16* __restrict__ o0, int n0,
    const float* __restrict__ i1, __bf16* __restrict__ o1, int n1,
    const float* __restrict__ i2, __bf16* __restrict__ o2, int n2,
    const float* __restrict__ i3, __bf16* __restrict__ o3, int n3)
{
  int gid = blockIdx.x * 256 + threadIdx.x;
  const int u0 = n0 >> 3, u1 = n1 >> 3, u2 = n2 >> 3, u3 = n3 >> 3;
  const float* in; __bf16* out;
  if (gid < u0) { in = i0; out = o0; }
  else if ((gid -= u0) < u1) { in = i1; out = o1; }
  else if ((gid -= u1) < u2) { in = i2; out = o2; }
  else if ((gid -= u2) < u3) { in = i3; out = o3; }
  else return;
  const int i = gid * 8;
  const float4 a = *reinterpret_cast<const float4*>(in + i);
  const float4 b = *reinterpret_cast<const float4*>(in + i + 4);
  bf16_8 v;
  v[0]=(__bf16)a.x; v[1]=(__bf16)a.y; v[2]=(__bf16)a.z; v[3]=(__bf16)a.w;
  v[4]=(__bf16)b.x; v[5]=(__bf16)b.y; v[6]=(__bf16)b.z; v[7]=(__bf16)b.w;
  *reinterpret_cast<bf16_8*>(out + i) = v;
}

// ---- MFMA bf16 GEMM (128x128, BK=64, XOR-swizzled LDS, XCD-swizzled grid) ----
// flags: 1=accumulate, 2=softplus, 4=bias
__global__ __launch_bounds__(256) void gemm_mfma(
    const __bf16* __restrict__ A, int lda,
    const __bf16* __restrict__ W, int ldw,
    const float* __restrict__ bias, float* __restrict__ C, int ldc,
    int K, int flags)
{
  __shared__ __bf16 As[128 * 64];
  __shared__ __bf16 Ws[128 * 64];
  const int tid  = threadIdx.x;
  const int lane = tid & 63;
  const int w    = tid >> 6;
  const int wr   = w >> 1, wc = w & 1;
  const int nwg  = gridDim.x * gridDim.y;
  const int swz  = xcd_swz(blockIdx.y * gridDim.x + blockIdx.x, nwg);
  const int bx   = swz % gridDim.x, by = swz / gridDim.x;
  const int row0 = by * 128, col0 = bx * 128;

  f32x4 acc[4][4] = {};

  for (int k0 = 0; k0 < K; k0 += 64) {
    #pragma unroll
    for (int j = 0; j < 4; ++j) {
      const int inst = w * 4 + j;
      const int row  = inst * 8 + (lane >> 3);
      const int lu   = (lane & 7) ^ (row & 7);
      __builtin_amdgcn_global_load_lds(
          (const __attribute__((address_space(1))) void*)(A + (size_t)(row0 + row) * lda + k0 + lu * 8),
          (__attribute__((address_space(3))) void*)(&As[inst * 512]), 16, 0, 0);
      __builtin_amdgcn_global_load_lds(
          (const __attribute__((address_space(1))) void*)(W + (size_t)(col0 + row) * ldw + k0 + lu * 8),
          (__attribute__((address_space(3))) void*)(&Ws[inst * 512]), 16, 0, 0);
    }
    __syncthreads();
    const int r16 = lane & 15;
    const int uq  = lane >> 4;
    #pragma unroll
    for (int ks = 0; ks < 2; ++ks) {
      bf16_8 af[4], bfr[4];
      #pragma unroll
      for (int m = 0; m < 4; ++m) {
        const int row = wr * 64 + m * 16 + r16;
        const int pu  = (ks * 4 + uq) ^ (row & 7);
        af[m] = *reinterpret_cast<const bf16_8*>(&As[row * 64 + pu * 8]);
      }
      #pragma unroll
      for (int n = 0; n < 4; ++n) {
        const int row = wc * 64 + n * 16 + r16;
        const int pu  = (ks * 4 + uq) ^ (row & 7);
        bfr[n] = *reinterpret_cast<const bf16_8*>(&Ws[row * 64 + pu * 8]);
      }
      #pragma unroll
      for (int m = 0; m < 4; ++m)
        #pragma unroll
        for (int n = 0; n < 4; ++n)
          acc[m][n] = __builtin_amdgcn_mfma_f32_16x16x32_bf16(af[m], bfr[n], acc[m][n], 0, 0, 0);
    }
    __syncthreads();
  }

  const int crow = (lane >> 4) * 4;
  const int ccol = lane & 15;
  #pragma unroll
  for (int m = 0; m < 4; ++m)
    #pragma unroll
    for (int n = 0; n < 4; ++n) {
      const int col = col0 + wc * 64 + n * 16 + ccol;
      const float bv = (flags & 4) ? bias[col] : 0.f;
      #pragma unroll
      for (int r = 0; r < 4; ++r) {
        const int row = row0 + wr * 64 + m * 16 + crow + r;
        float* cp = C + (size_t)row * ldc + col;
        float v = acc[m][n][r] + bv;
        if (flags & 2) v = softplus_f(v);
        if (flags & 1) v += *cp;
        *cp = v;
      }
    }
}

// split-K MFMA GEMM (lda=ldw=K)
__global__ __launch_bounds__(256) void gemm_mfma_sk(
    const __bf16* __restrict__ A, const __bf16* __restrict__ W,
    float* __restrict__ partials, int M, int N, int K, int Kc)
{
  __shared__ __bf16 As[128 * 64];
  __shared__ __bf16 Ws[128 * 64];
  const int tid  = threadIdx.x;
  const int lane = tid & 63;
  const int w    = tid >> 6;
  const int wr   = w >> 1, wc = w & 1;
  const int nwg  = gridDim.x * gridDim.y * gridDim.z;
  const int lin  = (blockIdx.z * gridDim.y + blockIdx.y) * gridDim.x + blockIdx.x;
  const int swz  = xcd_swz(lin, nwg);
  const int bx   = swz % gridDim.x;
  const int tmp  = swz / gridDim.x;
  const int by   = tmp % gridDim.y, bz = tmp / gridDim.y;
  const int row0 = by * 128, col0 = bx * 128;
  const int kbase = bz * Kc;

  f32x4 acc[4][4] = {};

  for (int k0 = kbase; k0 < kbase + Kc; k0 += 64) {
    #pragma unroll
    for (int j = 0; j < 4; ++j) {
      const int inst = w * 4 + j;
      const int row  = inst * 8 + (lane >> 3);
      const int lu   = (lane & 7) ^ (row & 7);
      __builtin_amdgcn_global_load_lds(
          (const __attribute__((address_space(1))) void*)(A + (size_t)(row0 + row) * K + k0 + lu * 8),
          (__attribute__((address_space(3))) void*)(&As[inst * 512]), 16, 0, 0);
      __builtin_amdgcn_global_load_lds(
          (const __attribute__((address_space(1))) void*)(W + (size_t)(col0 + row) * K + k0 + lu * 8),
          (__attribute__((address_space(3))) void*)(&Ws[inst * 512]), 16, 0, 0);
    }
    __syncthreads();
    const int r16 = lane & 15;
    const int uq  = lane >> 4;
    #pragma unroll
    for (int ks = 0; ks < 2; ++ks) {
      bf16_8 af[4], bfr[4];
      #pragma unroll
      for (int m = 0; m < 4; ++m) {
        const int row = wr * 64 + m * 16 + r16;
        const int pu  = (ks * 4 + uq) ^ (row & 7);
        af[m] = *reinterpret_cast<const bf16_8*>(&As[row * 64 + pu * 8]);
      }
      #pragma unroll
      for (int n = 0; n < 4; ++n) {
        const int row = wc * 64 + n * 16 + r16;
        const int pu  = (ks * 4 + uq) ^ (row & 7);
        bfr[n] = *reinterpret_cast<const bf16_8*>(&Ws[row * 64 + pu * 8]);
      }
      #pragma unroll
      for (int m = 0; m < 4; ++m)
        #pragma unroll
        for (int n = 0; n < 4; ++n)
          acc[m][n] = __builtin_amdgcn_mfma_f32_16x16x32_bf16(af[m], bfr[n], acc[m][n], 0, 0, 0);
    }
    __syncthreads();
  }

  float* base = partials + (size_t)bz * M * N;
  const int crow = (lane >> 4) * 4;
  const int ccol = lane & 15;
  #pragma unroll
  for (int m = 0; m < 4; ++m)
    #pragma unroll
    for (int n = 0; n < 4; ++n) {
      const int col = col0 + wc * 64 + n * 16 + ccol;
      #pragma unroll
      for (int r = 0; r < 4; ++r) {
        const int row = row0 + wr * 64 + m * 16 + crow + r;
        base[(size_t)row * N + col] = acc[m][n][r];
      }
    }
}

// generic reduce (xproj + final out-reduce)
__global__ __launch_bounds__(256) void mfma_sk_reduce(
    const float* __restrict__ partials, const float* __restrict__ bias,
    float* __restrict__ C, __bf16* __restrict__ Cbf,
    int elems, int ncols, int nz, int flags)
{
  const int i = (blockIdx.x * 256 + threadIdx.x) * 4;
  if (i >= elems) return;
  float4 s = *reinterpret_cast<const float4*>(partials + i);
  for (int z = 1; z < nz; ++z) {
    const float4 p = *reinterpret_cast<const float4*>(partials + (size_t)z * elems + i);
    s.x += p.x; s.y += p.y; s.z += p.z; s.w += p.w;
  }
  if (flags & 4) {
    const float4 bv = *reinterpret_cast<const float4*>(bias + (i % ncols));
    s.x += bv.x; s.y += bv.y; s.z += bv.z; s.w += bv.w;
  }
  if (flags & 1) {
    const float4 ov = *reinterpret_cast<const float4*>(C + i);
    s.x += ov.x; s.y += ov.y; s.z += ov.z; s.w += ov.w;
  }
  *reinterpret_cast<float4*>(C + i) = s;
  if (flags & 8) {
    bf16_4 b;
    b[0]=(__bf16)s.x; b[1]=(__bf16)s.y; b[2]=(__bf16)s.z; b[3]=(__bf16)s.w;
    *reinterpret_cast<bf16_4*>(Cbf + i) = b;
  }
}

// fused: reduce ZSPL split-K partials (+bias or +acc) -> h_buf, then LN -> bf16
__global__ __launch_bounds__(256) void reduce_ln_k(
    const float* __restrict__ partials, const float* __restrict__ bias,
    float* __restrict__ hbuf, const float* __restrict__ g,
    const float* __restrict__ b, __bf16* __restrict__ outbf, int flags)
{
  __shared__ float red[8];
  const int row = blockIdx.x;
  const int tid = threadIdx.x;
  const int c = tid * 4;
  const size_t off = (size_t)row * D_ + c;
  float4 v = *reinterpret_cast<const float4*>(partials + off);
  #pragma unroll
  for (int z = 1; z < ZSPL; ++z) {
    const float4 p = *reinterpret_cast<const float4*>(partials + (size_t)z * (L_*D_) + off);
    v.x += p.x; v.y += p.y; v.z += p.z; v.w += p.w;
  }
  if (flags & 4) {
    const float4 bv = *reinterpret_cast<const float4*>(bias + c);
    v.x += bv.x; v.y += bv.y; v.z += bv.z; v.w += bv.w;
  }
  if (flags & 1) {
    const float4 ov = *reinterpret_cast<const float4*>(hbuf + off);
    v.x += ov.x; v.y += ov.y; v.z += ov.z; v.w += ov.w;
  }
  *reinterpret_cast<float4*>(hbuf + off) = v;

  float s = v.x + v.y + v.z + v.w;
  #pragma unroll
  for (int o = 32; o; o >>= 1) s += __shfl_down(s, o, 64);
  if ((tid & 63) == 0) red[tid >> 6] = s;
  __syncthreads();
  const float m = (red[0] + red[1] + red[2] + red[3]) * (1.f / D_);
  float dx0 = v.x - m, dx1 = v.y - m, dx2 = v.z - m, dx3 = v.w - m;
  float ss = dx0*dx0 + dx1*dx1 + dx2*dx2 + dx3*dx3;
  #pragma unroll
  for (int o = 32; o; o >>= 1) ss += __shfl_down(ss, o, 64);
  if ((tid & 63) == 0) red[4 + (tid >> 6)] = ss;
  __syncthreads();
  const float var = (red[4] + red[5] + red[6] + red[7]) * (1.f / D_);
  const float rs = rsqrtf(var + 1e-5f);
  const float4 gv = *reinterpret_cast<const float4*>(g + c);
  const float4 bv = *reinterpret_cast<const float4*>(b + c);
  bf16_4 o;
  o[0] = (__bf16)(dx0 * rs * gv.x + bv.x);
  o[1] = (__bf16)(dx1 * rs * gv.y + bv.y);
  o[2] = (__bf16)(dx2 * rs * gv.z + bv.z);
  o[3] = (__bf16)(dx3 * rs * gv.w + bv.w);
  *reinterpret_cast<bf16_4*>(outbf + off) = o;
}

// layernorm, fp32 out (final LN)
__global__ __launch_bounds__(256) void layernorm_k(
    const float* __restrict__ x, const float* __restrict__ g,
    const float* __restrict__ b, float* __restrict__ out)
{
  __shared__ float red[8];
  const int row = blockIdx.x;
  const int tid = threadIdx.x;
  const float* xr = x + (size_t)row * D_;
  float4 v = *reinterpret_cast<const float4*>(xr + tid * 4);
  float s = v.x + v.y + v.z + v.w;
  #pragma unroll
  for (int off = 32; off; off >>= 1) s += __shfl_down(s, off, 64);
  if ((tid & 63) == 0) red[tid >> 6] = s;
  __syncthreads();
  const float m = (red[0] + red[1] + red[2] + red[3]) * (1.f / D_);
  float dx0 = v.x - m, dx1 = v.y - m, dx2 = v.z - m, dx3 = v.w - m;
  float ss = dx0*dx0 + dx1*dx1 + dx2*dx2 + dx3*dx3;
  #pragma unroll
  for (int off = 32; off; off >>= 1) ss += __shfl_down(ss, off, 64);
  if ((tid & 63) == 0) red[4 + (tid >> 6)] = ss;
  __syncthreads();
  const float var = (red[4] + red[5] + red[6] + red[7]) * (1.f / D_);
  const float rs = rsqrtf(var + 1e-5f);
  const int c = tid * 4;
  const float4 gv = *reinterpret_cast<const float4*>(g + c);
  const float4 bv = *reinterpret_cast<const float4*>(b + c);
  float4 o;
  o.x = dx0 * rs * gv.x + bv.x;
  o.y = dx1 * rs * gv.y + bv.y;
  o.z = dx2 * rs * gv.z + bv.z;
  o.w = dx3 * rs * gv.w + bv.w;
  *reinterpret_cast<float4*>(out + (size_t)row * D_ + c) = o;
}

// depthwise causal conv K=4 + bias + silu; 8 timesteps/thread; fp32 + bf16 out
__global__ __launch_bounds__(256) void conv_silu_k(
    const float* __restrict__ xz, const float* __restrict__ cw,
    const float* __restrict__ cb, float* __restrict__ u, __bf16* __restrict__ ub)
{
  const int e = blockIdx.x * 256 + threadIdx.x;
  const int t0 = blockIdx.y * 8;
  const float w0 = cw[e*4+0], w1 = cw[e*4+1], w2 = cw[e*4+2], w3 = cw[e*4+3];
  const float b = cb[e];
  float x0 = (t0 >= 3) ? xz[(size_t)(t0-3)*(2*ED_)+e] : 0.f;
  float x1 = (t0 >= 2) ? xz[(size_t)(t0-2)*(2*ED_)+e] : 0.f;
  float x2 = (t0 >= 1) ? xz[(size_t)(t0-1)*(2*ED_)+e] : 0.f;
  #pragma unroll
  for (int j = 0; j < 8; ++j) {
    const float x3 = xz[(size_t)(t0+j)*(2*ED_)+e];
    const float uv = silu_f(b + w0*x0 + w1*x1 + w2*x2 + w3*x3);
    u[(size_t)(t0+j)*ED_+e] = uv;
    ub[(size_t)(t0+j)*ED_+e] = (__bf16)uv;
    x0 = x1; x1 = x2; x2 = x3;
  }
}

// ---- chunked selective scan ----
// phase 1: 32-step tiles, chain unrolled x2. grid.y = NCH-1 (chunk 7's carry
// is never consumed by the phase-3 combine, so it is not computed).
__global__ __launch_bounds__(256) void scan_phase1(
    const float* __restrict__ delta, const float* __restrict__ u,
    const float* __restrict__ xdbl, const float* __restrict__ A_log,
    float* __restrict__ hend, float* __restrict__ Pend)
{
  __shared__ float dl[32][8], ul[32][8];
  __shared__ float bl[32][32];
  const int tid = threadIdx.x;
  const int n = tid & 31;
  const int c = tid >> 5;
  const int e0 = blockIdx.x * 8;
  const int e = e0 + c;
  const int ch = blockIdx.y;
  const float a = -expf(A_log[e * NST + n]);
  float h = 0.f, S = 0.f;
  const int t0 = ch * CHUNK;
  const int s_t = tid >> 3, s_e = tid & 7;       // 32 x 8
  const int b_t = tid >> 3, b_c = (tid & 7) * 4; // 32 x 8 float4 = 32x32

  float rg_d, rg_u;
  float4 rg_b;
  rg_d = delta[(size_t)(t0 + s_t) * ED_ + e0 + s_e];
  rg_u = u[(size_t)(t0 + s_t) * ED_ + e0 + s_e];
  rg_b = *reinterpret_cast<const float4*>(&xdbl[(size_t)(t0 + b_t) * 128 + 64 + b_c]);

  for (int tb = 0; tb < CHUNK; tb += 32) {
    dl[s_t][s_e] = rg_d;
    ul[s_t][s_e] = rg_u;
    *reinterpret_cast<float4*>(&bl[b_t][b_c]) = rg_b;
    __syncthreads();
    if (tb + 32 < CHUNK) {
      const int t = t0 + tb + 32 + s_t;
      rg_d = delta[(size_t)t * ED_ + e0 + s_e];
      rg_u = u[(size_t)t * ED_ + e0 + s_e];
      rg_b = *reinterpret_cast<const float4*>(&xdbl[(size_t)(t0 + tb + 32 + b_t) * 128 + 64 + b_c]);
    }
    #pragma unroll
    for (int jp = 0; jp < 16; ++jp) {
      const float sd1 = dl[2*jp][c],   uv1 = ul[2*jp][c],   B1 = bl[2*jp][n];
      const float sd2 = dl[2*jp+1][c], uv2 = ul[2*jp+1][c], B2 = bl[2*jp+1][n];
      const float dA1 = __expf(sd1 * a);
      const float dA2 = __expf(sd2 * a);
      const float b1 = sd1 * uv1 * B1;
      const float b2 = sd2 * uv2 * B2;
      h = fmaf(dA1 * dA2, h, fmaf(dA2, b1, b2));
      S += sd1 + sd2;
    }
    __syncthreads();
  }
  const int idx = ch * (ED_ * NST) + blockIdx.x * 256 + tid;
  hend[idx] = h;
  Pend[idx] = __expf(a * S);
}

// phase 3: inline h_in combine + pipelined LDS tiles (round-11 proven config)
__global__ __launch_bounds__(256, 7) void scan_phase3(
    const float* __restrict__ delta, const float* __restrict__ u,
    const float* __restrict__ xdbl, const float* __restrict__ A_log,
    const float* __restrict__ hend, const float* __restrict__ Pend,
    const float* __restrict__ Dp,
    const float* __restrict__ xz, __bf16* __restrict__ y)
{
  __shared__ float p_lds[8][16][33];
  __shared__ float dl[16][8], ul[16][8], zl[16][8];
  __shared__ float bc[16][64];
  const int tid = threadIdx.x;
  const int n = tid & 31;
  const int c = tid >> 5;
  const int e0 = blockIdx.x * 8;
  const int e = e0 + c;
  const int ch = blockIdx.y;
  const float a = -expf(A_log[e * NST + n]);
  const float dp = Dp[e];

  float h = 0.f;
  {
    const int sidx = blockIdx.x * 256 + tid;
    for (int cc = 0; cc < ch; ++cc) {
      const int off = cc * (ED_ * NST) + sidx;
      h = fmaf(Pend[off], h, hend[off]);
    }
  }

  const int t0 = ch * CHUNK;
  const int r = n & 15, half = n >> 4;
  const int s_t  = (tid & 127) >> 3;
  const int s_e  = tid & 7;
  const int b_t  = tid >> 4;
  const int b_c  = (tid & 15) * 4;

  float rg_a = 0.f, rg_z = 0.f;
  float4 rg_bc;
  {
    const int t = t0 + s_t;
    if (tid < 128) {
      rg_a = delta[(size_t)t * ED_ + e0 + s_e];
      rg_z = xz[(size_t)t * (2*ED_) + ED_ + e0 + s_e];
    } else {
      rg_a = u[(size_t)t * ED_ + e0 + s_e];
    }
    rg_bc = *reinterpret_cast<const float4*>(&xdbl[(size_t)(t0 + b_t) * 128 + 64 + b_c]);
  }

  for (int tb = 0; tb < CHUNK; tb += 16) {
    if (tid < 128) { dl[s_t][s_e] = rg_a; zl[s_t][s_e] = rg_z; }
    else          { ul[s_t][s_e] = rg_a; }
    *reinterpret_cast<float4*>(&bc[b_t][b_c]) = rg_bc;
    __syncthreads();
    if (tb + 16 < CHUNK) {
      const int t = t0 + tb + 16 + s_t;
      if (tid < 128) {
        rg_a = delta[(size_t)t * ED_ + e0 + s_e];
        rg_z = xz[(size_t)t * (2*ED_) + ED_ + e0 + s_e];
      } else {
        rg_a = u[(size_t)t * ED_ + e0 + s_e];
      }
      rg_bc = *reinterpret_cast<const float4*>(&xdbl[(size_t)(t0 + tb + 16 + b_t) * 128 + 64 + b_c]);
    }
    #pragma unroll
    for (int j = 0; j < 16; ++j) {
      const float sd = dl[j][c];
      const float uv = ul[j][c];
      const float Bv = bc[j][n];
      const float Cv = bc[j][32 + n];
      const float dA = __expf(sd * a);
      h = fmaf(dA, h, sd * uv * Bv);
      p_lds[c][j][n] = h * Cv;
    }
    __syncthreads();
    float s = 0.f;
    #pragma unroll
    for (int k = 0; k < 16; ++k) s += p_lds[c][r][half * 16 + k];
    s += __shfl_xor(s, 16, 64);
    if (half == 0) {
      const float uvt = ul[r][c];
      const float zv  = zl[r][c];
      y[(size_t)(t0 + tb + r) * ED_ + e] = (__bf16)((s + uvt * dp) * silu_f(zv));
    }
    __syncthreads();
  }
}

// column-mean partials (coalesced)
__global__ __launch_bounds__(256) void colmean_part_k(
    const float* __restrict__ hf, float* __restrict__ part)
{
  const int d = blockIdx.x * 256 + threadIdx.x;
  const int tc = blockIdx.y;
  float s = 0.f;
  #pragma unroll 8
  for (int j = 0; j < 32; ++j) s += hf[(size_t)(tc * 32 + j) * D_ + d];
  part[tc * D_ + d] = s;
}

// fused finalize + state projection
__global__ __launch_bounds__(256) void state_fused_k(
    const float* __restrict__ part, const float* __restrict__ spw,
    const float* __restrict__ spb, float* __restrict__ out)
{
  __shared__ float red[4];
  const int nidx = blockIdx.x;
  const int tid = threadIdx.x;
  float s = 0.f;
  for (int d = tid; d < D_; d += 256) {
    float cm = 0.f;
    #pragma unroll
    for (int c = 0; c < 32; ++c) cm += part[c * D_ + d];
    s += cm * (1.f / L_) * spw[(size_t)nidx * D_ + d];
  }
  #pragma unroll
  for (int off = 32; off; off >>= 1) s += __shfl_down(s, off, 64);
  if ((tid & 63) == 0) red[tid >> 6] = s;
  __syncthreads();
  if (tid == 0) out[nidx] = red[0] + red[1] + red[2] + red[3] + spb[nidx];
}

extern "C" void kernel_launch(void* const* d_in, const int* in_sizes, int n_in,
                              void* d_out, int out_size, void* d_ws, size_t ws_size,
                              hipStream_t stream) {
  const float* x        = (const float*)d_in[0];
  const float* Wi       = (const float*)d_in[1];
  const float* bi       = (const float*)d_in[2];
  const float* ln_g     = (const float*)d_in[3];
  const float* ln_b     = (const float*)d_in[4];
  const float* in_w     = (const float*)d_in[5];
  const float* conv_w   = (const float*)d_in[6];
  const float* conv_b   = (const float*)d_in[7];
  const float* xproj_w  = (const float*)d_in[8];
  const float* dtproj_w = (const float*)d_in[9];
  const float* dtproj_b = (const float*)d_in[10];
  const float* A_log    = (const float*)d_in[11];
  const float* Dp       = (const float*)d_in[12];
  const float* out_w    = (const float*)d_in[13];
  const float* fn_g     = (const float*)d_in[14];
  const float* fn_b     = (const float*)d_in[15];
  const float* sp_w     = (const float*)d_in[16];
  const float* sp_b     = (const float*)d_in[17];
  float* out  = (float*)d_out;
  float* ws_f = (float*)d_ws;

  float* h_buf  = ws_f;                // 1048576
  float* xz     = ws_f + 1048576;      // 4194304
  float* u_buf  = ws_f + 5242880;      // 2097152
  float* xdbl   = ws_f + 7340032;      // 131072
  float* delta  = ws_f + 7471104;      // 2097152 (also xproj partials)
  float* hend   = ws_f + 9568256;      // 524288
  float* pend   = ws_f + 10092544;     // 524288
  __bf16* nbf   = (__bf16*)(ws_f + 10617856);  // 1M bf16
  __bf16* ybf   = (__bf16*)(ws_f + 11142144);  // 2M bf16
  __bf16* wbf   = (__bf16*)(ws_f + 12190720);  // 8M bf16 (in_w)
  __bf16* xdblbf= (__bf16*)(ws_f + 16385024);  // 128K bf16
  __bf16* dtwbf = (__bf16*)(ws_f + 16450560);  // 128K bf16
  __bf16* ubf   = (__bf16*)(ws_f + 16516096);  // 2M bf16
  __bf16* xpbf  = (__bf16*)(ws_f + 17564672);  // 256K bf16
  __bf16* owbf  = (__bf16*)(ws_f + 17695744);  // 2M bf16 (out_w)
  float* skmf   = u_buf;               // MFMA split-K partials overlay (Wi/out)
  float* skxp   = delta;               // xproj split-K partials overlay
  float* cmpart = hend;                // colmean partials overlay

  const dim3 blk(256);

  // prologue: convert x + Wi; Wi GEMM split-K=4; fused reduce + LN(block 0)
  f2bf4_k<<<1024, blk, 0, stream>>>(x, nbf, L_*D_, Wi, wbf, D_*D_,
                                    x, nbf, 0, x, nbf, 0);
  gemm_mfma_sk<<<dim3(D_/128, L_/128, ZSPL), blk, 0, stream>>>(
      nbf, wbf, skmf, L_, D_, D_, D_/ZSPL);
  reduce_ln_k<<<L_, blk, 0, stream>>>(
      skmf, bi, h_buf, ln_g, ln_b, nbf, 4);

  for (int i = 0; i < NB_; ++i) {
    f2bf4_k<<<3264, blk, 0, stream>>>(
        in_w    + (size_t)i*2*ED_*D_, wbf,   2*ED_*D_,
        xproj_w + (size_t)i*128*ED_,  xpbf,  128*ED_,
        dtproj_w+ (size_t)i*ED_*DTR_, dtwbf, ED_*DTR_,
        out_w   + (size_t)i*D_*ED_,   owbf,  D_*ED_);
    // xz = normed @ in_w^T  (nbf prepared by previous reduce_ln)
    gemm_mfma<<<dim3(2*ED_/128, L_/128), blk, 0, stream>>>(
        nbf, D_, wbf, D_, nullptr, xz, 2*ED_, D_, 0);
    conv_silu_k<<<dim3(ED_/256, L_/8), blk, 0, stream>>>(
        xz, conv_w + (size_t)i*ED_*KCONV, conv_b + (size_t)i*ED_, u_buf, ubf);
    // x_dbl = u @ xproj^T  (bf16 MFMA split-K=16)
    gemm_mfma_sk<<<dim3(1, L_/128, XPZ), blk, 0, stream>>>(
        ubf, xpbf, skxp, L_, 128, ED_, ED_/XPZ);
    mfma_sk_reduce<<<dim3(L_*128/4/256), blk, 0, stream>>>(
        skxp, nullptr, xdbl, xdblbf, L_*128, 128, XPZ, 8);
    // delta = softplus(dt @ dtproj^T + b)  (bf16 MFMA, K=64)
    gemm_mfma<<<dim3(ED_/128, L_/128), blk, 0, stream>>>(
        xdblbf, 128, dtwbf, DTR_, dtproj_b + (size_t)i*ED_, delta, ED_, DTR_, 2 | 4);
    // chunked scan (phase1 skips chunk 7 — its carry is never consumed)
    scan_phase1<<<dim3(ED_/8, NCH - 1), blk, 0, stream>>>(
        delta, u_buf, xdbl, A_log + (size_t)i*ED_*NST, hend, pend);
    scan_phase3<<<dim3(ED_/8, NCH), blk, 0, stream>>>(
        delta, u_buf, xdbl, A_log + (size_t)i*ED_*NST, hend, pend,
        Dp + (size_t)i*ED_, xz, ybf);
    // h += y @ out_w^T (split-K=4); fused reduce(+acc)+LN for next block
    gemm_mfma_sk<<<dim3(D_/128, L_/128, ZSPL), blk, 0, stream>>>(
        ybf, owbf, skmf, L_, D_, ED_, ED_/ZSPL);
    if (i < NB_ - 1) {
      reduce_ln_k<<<L_, blk, 0, stream>>>(
          skmf, nullptr, h_buf, ln_g + (i+1)*D_, ln_b + (i+1)*D_, nbf, 1);
    } else {
      mfma_sk_reduce<<<dim3(L_*D_/4/256), blk, 0, stream>>>(
          skmf, nullptr, h_buf, nullptr, L_*D_, D_, ZSPL, 1);
    }
  }

  layernorm_k<<<L_, blk, 0, stream>>>(h_buf, fn_g, fn_b, out);
  colmean_part_k<<<dim3(D_/256, 32), blk, 0, stream>>>(out, cmpart);
  state_fused_k<<<NST, blk, 0, stream>>>(cmpart, sp_w, sp_b, out + (size_t)L_*D_);
}